// Round 1
// baseline (644.860 us; speedup 1.0000x reference)
//
#include <hip/hip_runtime.h>
#include <hip/hip_bf16.h>
#include <math.h>

// MHSA: B=8, DIM=512, H=W=32, HEAD=8, DH=64, N=1024
// Pipeline:
//  1) qkv_kernel   : 3 GEMMs (1x1 conv). K gets R = r_h+r_w folded in (KR).
//                    Layouts: QT[b][hd][d][n], KR[b][hd][d][m], VT[b][hd][n][d]
//  2) stats_kernel : recompute logits L = QT^T * KR per 64x64 tile, online
//                    (max,sumexp) per block -> pstats
//  3) combine      : per-batch logsumexp-combine of 128 partials -> gstats
//  4) pv_kernel    : recompute logits, attn = exp(L-gmax)/gsum, F = V*A,
//                    fused 2x2 avg-pool, fp32 out
#define BB   8
#define DIMC 512
#define HEAD 8
#define DH   64
#define NN   1024
#define HW   32

__global__ __launch_bounds__(256)
void qkv_kernel(const float* __restrict__ x,
                const float* __restrict__ wq_w, const float* __restrict__ wq_b,
                const float* __restrict__ wk_w, const float* __restrict__ wk_b,
                const float* __restrict__ wv_w, const float* __restrict__ wv_b,
                const float* __restrict__ r_h, const float* __restrict__ r_w,
                float* __restrict__ QT, float* __restrict__ KR, float* __restrict__ VT)
{
    const int tid = threadIdx.x;
    const int z   = blockIdx.z;            // 0=q, 1=k(+r), 2=v
    const int b   = blockIdx.x >> 4;
    const int nBase = (blockIdx.x & 15) << 6;
    const int hd  = blockIdx.y;
    const int oBase = hd << 6;

    const float* wgt  = (z == 0) ? wq_w : (z == 1) ? wk_w : wv_w;
    const float* bias = (z == 0) ? wq_b : (z == 1) ? wk_b : wv_b;

    __shared__ float Ws[16][68];   // [c][o]
    __shared__ float Xs[16][68];   // [c][n]

    const int tx = tid & 15;       // n group
    const int ty = tid >> 4;       // o group

    float acc[4][4];
    #pragma unroll
    for (int i = 0; i < 4; ++i)
        #pragma unroll
        for (int j = 0; j < 4; ++j) acc[i][j] = 0.f;

    const int lo = tid & 63;       // o for W load
    const int lq = tid >> 6;       // c-quad for W load

    for (int c0 = 0; c0 < DIMC; c0 += 16) {
        // W tile 16c x 64o (transposed store)
        float4 wv4 = *(const float4*)&wgt[(size_t)(oBase + lo) * DIMC + c0 + (lq << 2)];
        Ws[(lq << 2) + 0][lo] = wv4.x;
        Ws[(lq << 2) + 1][lo] = wv4.y;
        Ws[(lq << 2) + 2][lo] = wv4.z;
        Ws[(lq << 2) + 3][lo] = wv4.w;
        // X tile 16c x 64n (coalesced)
        const int xc = tid >> 4;
        const int xn = (tid & 15) << 2;
        float4 xv4 = *(const float4*)&x[((size_t)b * DIMC + c0 + xc) * NN + nBase + xn];
        *(float4*)&Xs[xc][xn] = xv4;
        __syncthreads();
        #pragma unroll
        for (int kk = 0; kk < 16; ++kk) {
            float4 a4 = *(const float4*)&Ws[kk][ty << 2];
            float4 b4 = *(const float4*)&Xs[kk][tx << 2];
            float av[4] = {a4.x, a4.y, a4.z, a4.w};
            float bv[4] = {b4.x, b4.y, b4.z, b4.w};
            #pragma unroll
            for (int i = 0; i < 4; ++i)
                #pragma unroll
                for (int j = 0; j < 4; ++j)
                    acc[i][j] = fmaf(av[i], bv[j], acc[i][j]);
        }
        __syncthreads();
    }

    const size_t bh = (size_t)(b * HEAD + hd);
    if (z == 0) {
        // QT[d][n]: float4 over n
        #pragma unroll
        for (int i = 0; i < 4; ++i) {
            int d = (ty << 2) + i;
            float bia = bias[oBase + d];
            float4 v4;
            v4.x = acc[i][0] + bia; v4.y = acc[i][1] + bia;
            v4.z = acc[i][2] + bia; v4.w = acc[i][3] + bia;
            *(float4*)&QT[((bh << 6) + d) * NN + nBase + (tx << 2)] = v4;
        }
    } else if (z == 1) {
        // KR[d][m] = K + r_h[d][m%32] + r_w[d][m/32]
        #pragma unroll
        for (int i = 0; i < 4; ++i) {
            int d = (ty << 2) + i;
            float bia = bias[oBase + d];
            const float* rh = &r_h[(size_t)(oBase + d) * HW];
            const float* rw = &r_w[(size_t)(oBase + d) * HW];
            float4 v4;
            #pragma unroll
            for (int j = 0; j < 4; ++j) {
                int m = nBase + (tx << 2) + j;
                ((float*)&v4)[j] = acc[i][j] + bia + rh[m & 31] + rw[m >> 5];
            }
            *(float4*)&KR[((bh << 6) + d) * NN + nBase + (tx << 2)] = v4;
        }
    } else {
        // VT[n][d]: float4 over d
        #pragma unroll
        for (int j = 0; j < 4; ++j) {
            int n = nBase + (tx << 2) + j;
            float4 v4;
            #pragma unroll
            for (int i = 0; i < 4; ++i)
                ((float*)&v4)[i] = acc[i][j] + bias[oBase + (ty << 2) + i];
            *(float4*)&VT[(bh * NN + n) * DH + (ty << 2)] = v4;
        }
    }
}

__global__ __launch_bounds__(256)
void stats_kernel(const float* __restrict__ QT, const float* __restrict__ KR,
                  float* __restrict__ pstats)
{
    const int tid = threadIdx.x;
    const int mt = blockIdx.x, hd = blockIdx.y, b = blockIdx.z;
    const int mBase = mt << 6;
    const size_t bh = (size_t)(b * HEAD + hd);
    const float* KRp = KR + (bh << 6) * NN;
    const float* QTp = QT + (bh << 6) * NN;

    __shared__ float KRs[64][68];
    __shared__ float Qs[64][68];
    __shared__ float red[2][256];

    #pragma unroll
    for (int q = 0; q < 4; ++q) {
        int idx = tid + q * 256;
        int row = idx >> 4;
        int c4 = (idx & 15) << 2;
        *(float4*)&KRs[row][c4] = *(const float4*)&KRp[(size_t)row * NN + mBase + c4];
    }

    const int tx = tid & 15, ty = tid >> 4;
    float m_r = -1e30f, s_r = 0.f;

    for (int nt = 0; nt < 16; ++nt) {
        const int nB = nt << 6;
        #pragma unroll
        for (int q = 0; q < 4; ++q) {
            int idx = tid + q * 256;
            int row = idx >> 4;
            int c4 = (idx & 15) << 2;
            *(float4*)&Qs[row][c4] = *(const float4*)&QTp[(size_t)row * NN + nB + c4];
        }
        __syncthreads();

        float lacc[4][4] = {};
        #pragma unroll
        for (int kk = 0; kk < 64; ++kk) {
            float4 a4 = *(const float4*)&Qs[kk][ty << 2];
            float4 b4 = *(const float4*)&KRs[kk][tx << 2];
            float av[4] = {a4.x, a4.y, a4.z, a4.w};
            float bv[4] = {b4.x, b4.y, b4.z, b4.w};
            #pragma unroll
            for (int i = 0; i < 4; ++i)
                #pragma unroll
                for (int j = 0; j < 4; ++j)
                    lacc[i][j] = fmaf(av[i], bv[j], lacc[i][j]);
        }
        // tile max, then rescale running sum once (short dependency chain)
        float tmax = -1e30f;
        #pragma unroll
        for (int i = 0; i < 4; ++i)
            #pragma unroll
            for (int j = 0; j < 4; ++j) tmax = fmaxf(tmax, lacc[i][j]);
        float nm = fmaxf(m_r, tmax);
        s_r *= __expf(m_r - nm);
        float t = 0.f;
        #pragma unroll
        for (int i = 0; i < 4; ++i)
            #pragma unroll
            for (int j = 0; j < 4; ++j) t += __expf(lacc[i][j] - nm);
        s_r += t;
        m_r = nm;
        __syncthreads();
    }

    red[0][tid] = m_r; red[1][tid] = s_r;
    __syncthreads();
    for (int off = 128; off > 0; off >>= 1) {
        if (tid < off) {
            float m2 = red[0][tid + off], s2 = red[1][tid + off];
            float M = fmaxf(red[0][tid], m2);
            red[1][tid] = red[1][tid] * __expf(red[0][tid] - M) + s2 * __expf(m2 - M);
            red[0][tid] = M;
        }
        __syncthreads();
    }
    if (tid == 0) {
        pstats[((b << 7) + (hd << 4) + mt) * 2 + 0] = red[0][0];
        pstats[((b << 7) + (hd << 4) + mt) * 2 + 1] = red[1][0];
    }
}

__global__ __launch_bounds__(128)
void combine_kernel(const float* __restrict__ pstats, float* __restrict__ gstats)
{
    const int b = blockIdx.x, tid = threadIdx.x;
    __shared__ float rm[128], rs[128];
    rm[tid] = pstats[((b << 7) + tid) * 2 + 0];
    rs[tid] = pstats[((b << 7) + tid) * 2 + 1];
    __syncthreads();
    for (int off = 64; off > 0; off >>= 1) {
        if (tid < off) {
            float m2 = rm[tid + off], s2 = rs[tid + off];
            float M = fmaxf(rm[tid], m2);
            rs[tid] = rs[tid] * __expf(rm[tid] - M) + s2 * __expf(m2 - M);
            rm[tid] = M;
        }
        __syncthreads();
    }
    if (tid == 0) { gstats[b * 2] = rm[0]; gstats[b * 2 + 1] = rs[0]; }
}

__global__ __launch_bounds__(256)
void pv_kernel(const float* __restrict__ QT, const float* __restrict__ KR,
               const float* __restrict__ VT, const float* __restrict__ gstats,
               float* __restrict__ out)
{
    const int tid = threadIdx.x;
    const int mt = blockIdx.x, hd = blockIdx.y, b = blockIdx.z;
    const int mBase = mt << 6;
    const size_t bh = (size_t)(b * HEAD + hd);
    const float* KRp = KR + (bh << 6) * NN;
    const float* QTp = QT + (bh << 6) * NN;
    const float* VTp = VT + bh * NN * DH;

    __shared__ float KRs[64][68];  // [d][m]; reused as F[d][m] for pooling
    __shared__ float QAs[64][68];  // Q tile [d][n], then attn tile [n][m]
    __shared__ float Vs[64][68];   // [n][d]

    const float gmax = gstats[b * 2];
    const float ginv = 1.f / gstats[b * 2 + 1];

    #pragma unroll
    for (int q = 0; q < 4; ++q) {
        int idx = tid + q * 256;
        int row = idx >> 4;
        int c4 = (idx & 15) << 2;
        *(float4*)&KRs[row][c4] = *(const float4*)&KRp[(size_t)row * NN + mBase + c4];
    }

    const int tx = tid & 15, ty = tid >> 4;
    float facc[4][4] = {};

    for (int nt = 0; nt < 16; ++nt) {
        const int nB = nt << 6;
        __syncthreads();  // prev iter PV reads done before overwrite
        #pragma unroll
        for (int q = 0; q < 4; ++q) {
            int idx = tid + q * 256;
            int row = idx >> 4;
            int c4 = (idx & 15) << 2;
            *(float4*)&QAs[row][c4] = *(const float4*)&QTp[(size_t)row * NN + nB + c4];
            *(float4*)&Vs[row][c4]  = *(const float4*)&VTp[(size_t)(nB + row) * DH + c4];
        }
        __syncthreads();
        // logits L[n,m]
        float lacc[4][4] = {};
        #pragma unroll
        for (int kk = 0; kk < 64; ++kk) {
            float4 a4 = *(const float4*)&QAs[kk][ty << 2];
            float4 b4 = *(const float4*)&KRs[kk][tx << 2];
            float av[4] = {a4.x, a4.y, a4.z, a4.w};
            float bv[4] = {b4.x, b4.y, b4.z, b4.w};
            #pragma unroll
            for (int i = 0; i < 4; ++i)
                #pragma unroll
                for (int j = 0; j < 4; ++j)
                    lacc[i][j] = fmaf(av[i], bv[j], lacc[i][j]);
        }
        __syncthreads();  // all Q reads done before attn overwrites QAs
        #pragma unroll
        for (int i = 0; i < 4; ++i)
            #pragma unroll
            for (int j = 0; j < 4; ++j)
                QAs[(ty << 2) + i][(tx << 2) + j] = __expf(lacc[i][j] - gmax) * ginv;
        __syncthreads();
        // F[d,m] += sum_n V[d,n] * A[n,m]
        #pragma unroll
        for (int kk = 0; kk < 64; ++kk) {
            float4 a4 = *(const float4*)&Vs[kk][ty << 2];
            float4 b4 = *(const float4*)&QAs[kk][tx << 2];
            float av[4] = {a4.x, a4.y, a4.z, a4.w};
            float bv[4] = {b4.x, b4.y, b4.z, b4.w};
            #pragma unroll
            for (int i = 0; i < 4; ++i)
                #pragma unroll
                for (int j = 0; j < 4; ++j)
                    facc[i][j] = fmaf(av[i], bv[j], facc[i][j]);
        }
    }
    __syncthreads();
    // stage F into LDS (reuse KRs) for cross-thread 2x2 pooling
    #pragma unroll
    for (int i = 0; i < 4; ++i)
        #pragma unroll
        for (int j = 0; j < 4; ++j)
            KRs[(ty << 2) + i][(tx << 2) + j] = facc[i][j];
    __syncthreads();
    // 64 m-cols = spatial rows h=2*mt, 2*mt+1 -> pooled row ho=mt
    #pragma unroll
    for (int q = 0; q < 4; ++q) {
        int idx = (tid << 2) + q;     // 0..1023
        int d = idx >> 4;
        int wo = idx & 15;
        float v = 0.25f * (KRs[d][2 * wo] + KRs[d][2 * wo + 1] +
                           KRs[d][32 + 2 * wo] + KRs[d][32 + 2 * wo + 1]);
        out[((size_t)(b * DIMC + (hd << 6) + d) * 16 + mt) * 16 + wo] = v;
    }
}

extern "C" void kernel_launch(void* const* d_in, const int* in_sizes, int n_in,
                              void* d_out, int out_size, void* d_ws, size_t ws_size,
                              hipStream_t stream)
{
    const float* x    = (const float*)d_in[0];
    const float* wq_w = (const float*)d_in[1];
    const float* wq_b = (const float*)d_in[2];
    const float* wk_w = (const float*)d_in[3];
    const float* wk_b = (const float*)d_in[4];
    const float* wv_w = (const float*)d_in[5];
    const float* wv_b = (const float*)d_in[6];
    const float* r_h  = (const float*)d_in[7];
    const float* r_w  = (const float*)d_in[8];
    float* out = (float*)d_out;

    float* ws = (float*)d_ws;
    const size_t projN = (size_t)BB * HEAD * DH * NN;   // 4,194,304 floats
    float* QT = ws;
    float* KR = QT + projN;
    float* VT = KR + projN;
    float* pstats = VT + projN;          // B*128*2
    float* gstats = pstats + BB * 128 * 2;

    qkv_kernel<<<dim3(128, 8, 3), 256, 0, stream>>>(x, wq_w, wq_b, wk_w, wk_b,
                                                    wv_w, wv_b, r_h, r_w, QT, KR, VT);
    stats_kernel<<<dim3(16, 8, 8), 256, 0, stream>>>(QT, KR, pstats);
    combine_kernel<<<dim3(8), 128, 0, stream>>>(pstats, gstats);
    pv_kernel<<<dim3(16, 8, 8), 256, 0, stream>>>(QT, KR, VT, gstats, out);
}

// Round 2
// 400.816 us; speedup vs baseline: 1.6089x; 1.6089x over previous
//
#include <hip/hip_runtime.h>
#include <hip/hip_bf16.h>
#include <math.h>

// MHSA: B=8, DIM=512, H=W=32, HEAD=8, DH=64, N=1024
// Round 2: split-bf16 MFMA for logits (stats + pv) and PV.
//  qkv_kernel : fp32 GEMMs; epilogue writes hi/lo bf16:
//               Q[bh][n][d], K(+R)[bh][m][d], V[bh][d][n]
//  stats      : S = 3-term split MFMA, online (max,sumexp) -> pstats
//  combine    : per-batch logsumexp combine -> gstats
//  pv         : recompute S, A=exp(S-gmax)/gsum split to bf16,
//               F = A*V via 3-term MFMA, fused 2x2 avg-pool
#define BB   8
#define DIMC 512
#define HEAD 8
#define DH   64
#define NN   1024
#define HW   32

typedef __attribute__((ext_vector_type(8))) __bf16 bf16x8;
typedef __attribute__((ext_vector_type(4))) float  f32x4;

#define MFMA16(a, b, c) __builtin_amdgcn_mfma_f32_16x16x32_bf16((a), (b), (c), 0, 0, 0)

// swizzled element offset in a [64 rows][64 bf16] LDS tile (rows = 128 B).
// XOR of byte-bits 4..6 with row&7 -> conflict-free ds_read_b128 (T2).
__device__ __forceinline__ int SW(int row, int col) {
    return (row << 6) + (col ^ ((row & 7) << 3));
}

__device__ __forceinline__ unsigned short bfh(float v) {   // fp32 -> bf16 (RNE)
    unsigned int u = __float_as_uint(v);
    return (unsigned short)((u + 0x7fffu + ((u >> 16) & 1u)) >> 16);
}
__device__ __forceinline__ float bf2f(unsigned short h) {
    return __uint_as_float(((unsigned int)h) << 16);
}

__global__ __launch_bounds__(256)
void qkv_kernel(const float* __restrict__ x,
                const float* __restrict__ wq_w, const float* __restrict__ wq_b,
                const float* __restrict__ wk_w, const float* __restrict__ wk_b,
                const float* __restrict__ wv_w, const float* __restrict__ wv_b,
                const float* __restrict__ r_h, const float* __restrict__ r_w,
                unsigned short* __restrict__ Qh, unsigned short* __restrict__ Ql,
                unsigned short* __restrict__ Kh, unsigned short* __restrict__ Kl,
                unsigned short* __restrict__ Vh, unsigned short* __restrict__ Vl)
{
    const int tid = threadIdx.x;
    const int z   = blockIdx.z;            // 0=q, 1=k(+r), 2=v
    const int b   = blockIdx.x >> 4;
    const int nBase = (blockIdx.x & 15) << 6;
    const int hd  = blockIdx.y;
    const int oBase = hd << 6;

    const float* wgt  = (z == 0) ? wq_w : (z == 1) ? wk_w : wv_w;
    const float* bias = (z == 0) ? wq_b : (z == 1) ? wk_b : wv_b;

    __shared__ float Ws[16][68];   // [c][o]
    __shared__ float Xs[16][68];   // [c][n]

    const int tx = tid & 15;       // n group
    const int ty = tid >> 4;       // o group

    float acc[4][4];
    #pragma unroll
    for (int i = 0; i < 4; ++i)
        #pragma unroll
        for (int j = 0; j < 4; ++j) acc[i][j] = 0.f;

    const int lo = tid & 63;
    const int lq = tid >> 6;

    for (int c0 = 0; c0 < DIMC; c0 += 16) {
        float4 wv4 = *(const float4*)&wgt[(size_t)(oBase + lo) * DIMC + c0 + (lq << 2)];
        Ws[(lq << 2) + 0][lo] = wv4.x;
        Ws[(lq << 2) + 1][lo] = wv4.y;
        Ws[(lq << 2) + 2][lo] = wv4.z;
        Ws[(lq << 2) + 3][lo] = wv4.w;
        const int xc = tid >> 4;
        const int xn = (tid & 15) << 2;
        float4 xv4 = *(const float4*)&x[((size_t)b * DIMC + c0 + xc) * NN + nBase + xn];
        *(float4*)&Xs[xc][xn] = xv4;
        __syncthreads();
        #pragma unroll
        for (int kk = 0; kk < 16; ++kk) {
            float4 a4 = *(const float4*)&Ws[kk][ty << 2];
            float4 b4 = *(const float4*)&Xs[kk][tx << 2];
            float av[4] = {a4.x, a4.y, a4.z, a4.w};
            float bv[4] = {b4.x, b4.y, b4.z, b4.w};
            #pragma unroll
            for (int i = 0; i < 4; ++i)
                #pragma unroll
                for (int j = 0; j < 4; ++j)
                    acc[i][j] = fmaf(av[i], bv[j], acc[i][j]);
        }
        __syncthreads();
    }

    const size_t bh = (size_t)(b * HEAD + hd);
    if (z == 0) {
        // Q[bh][n][d] hi/lo, 4 consecutive d per store
        #pragma unroll
        for (int j = 0; j < 4; ++j) {
            int n = nBase + (tx << 2) + j;
            union { unsigned short u[4]; uint2 v; } ph, pl;
            #pragma unroll
            for (int i = 0; i < 4; ++i) {
                float val = acc[i][j] + bias[oBase + (ty << 2) + i];
                unsigned short hh = bfh(val);
                ph.u[i] = hh;
                pl.u[i] = bfh(val - bf2f(hh));
            }
            size_t off = (((size_t)bh * NN + n) << 6) + (ty << 2);
            *(uint2*)&Qh[off] = ph.v;
            *(uint2*)&Ql[off] = pl.v;
        }
    } else if (z == 1) {
        // K[bh][m][d] hi/lo with R = r_h + r_w folded in
        #pragma unroll
        for (int j = 0; j < 4; ++j) {
            int m = nBase + (tx << 2) + j;
            union { unsigned short u[4]; uint2 v; } ph, pl;
            #pragma unroll
            for (int i = 0; i < 4; ++i) {
                int d = (ty << 2) + i;
                float val = acc[i][j] + bias[oBase + d]
                          + r_h[(size_t)(oBase + d) * HW + (m & 31)]
                          + r_w[(size_t)(oBase + d) * HW + (m >> 5)];
                unsigned short hh = bfh(val);
                ph.u[i] = hh;
                pl.u[i] = bfh(val - bf2f(hh));
            }
            size_t off = (((size_t)bh * NN + m) << 6) + (ty << 2);
            *(uint2*)&Kh[off] = ph.v;
            *(uint2*)&Kl[off] = pl.v;
        }
    } else {
        // V[bh][d][n] hi/lo, 4 consecutive n per store
        #pragma unroll
        for (int i = 0; i < 4; ++i) {
            int d = (ty << 2) + i;
            union { unsigned short u[4]; uint2 v; } ph, pl;
            #pragma unroll
            for (int j = 0; j < 4; ++j) {
                float val = acc[i][j] + bias[oBase + d];
                unsigned short hh = bfh(val);
                ph.u[j] = hh;
                pl.u[j] = bfh(val - bf2f(hh));
            }
            size_t off = (((size_t)bh << 6) + d) * NN + nBase + (tx << 2);
            *(uint2*)&Vh[off] = ph.v;
            *(uint2*)&Vl[off] = pl.v;
        }
    }
}

__global__ __launch_bounds__(256)
void stats_kernel(const unsigned short* __restrict__ Qh, const unsigned short* __restrict__ Ql,
                  const unsigned short* __restrict__ Kh, const unsigned short* __restrict__ Kl,
                  float* __restrict__ pstats)
{
    const int tid = threadIdx.x;
    const int mt = blockIdx.x, hd = blockIdx.y, b = blockIdx.z;
    const int mBase = mt << 6;
    const int bh = b * HEAD + hd;
    const int lane = tid & 63;
    const int w = tid >> 6;

    __shared__ __align__(16) unsigned short sm[8192];   // two [64][64] bf16 tiles
    unsigned short* Th = sm;
    unsigned short* Tl = sm + 4096;

    // ---- stage K tile (hi/lo), hoist B-fragments to registers ----
    {
        const unsigned short* kh = Kh + (((size_t)bh * NN + mBase) << 6);
        const unsigned short* kl = Kl + (((size_t)bh * NN + mBase) << 6);
        #pragma unroll
        for (int p = 0; p < 2; ++p) {
            int idx = (p << 8) + tid;
            int row = idx >> 3, c8 = (idx & 7) << 3;
            *(float4*)&Th[SW(row, c8)] = *(const float4*)&kh[(row << 6) + c8];
            *(float4*)&Tl[SW(row, c8)] = *(const float4*)&kl[(row << 6) + c8];
        }
    }
    __syncthreads();
    bf16x8 kfh[4][2], kfl[4][2];    // [m-tile][k-step]
    {
        const int r0 = lane & 15, c0 = (lane >> 4) << 3;
        #pragma unroll
        for (int t = 0; t < 4; ++t)
            #pragma unroll
            for (int s = 0; s < 2; ++s) {
                kfh[t][s] = *(const bf16x8*)&Th[SW(t * 16 + r0, s * 32 + c0)];
                kfl[t][s] = *(const bf16x8*)&Tl[SW(t * 16 + r0, s * 32 + c0)];
            }
    }
    __syncthreads();

    const unsigned short* qh = Qh + ((size_t)bh * NN << 6);
    const unsigned short* ql = Ql + ((size_t)bh * NN << 6);

    float m_r = -1e30f, s_r = 0.f;

    for (int nt = 0; nt < 16; ++nt) {
        const int nB = nt << 6;
        #pragma unroll
        for (int p = 0; p < 2; ++p) {
            int idx = (p << 8) + tid;
            int row = idx >> 3, c8 = (idx & 7) << 3;
            *(float4*)&Th[SW(row, c8)] = *(const float4*)&qh[((size_t)(nB + row) << 6) + c8];
            *(float4*)&Tl[SW(row, c8)] = *(const float4*)&ql[((size_t)(nB + row) << 6) + c8];
        }
        __syncthreads();

        f32x4 sacc[4];
        #pragma unroll
        for (int t = 0; t < 4; ++t) sacc[t] = (f32x4){0.f, 0.f, 0.f, 0.f};

        #pragma unroll
        for (int s = 0; s < 2; ++s) {
            int ar = (w << 4) + (lane & 15);
            int ac = s * 32 + ((lane >> 4) << 3);
            bf16x8 ah = *(const bf16x8*)&Th[SW(ar, ac)];
            bf16x8 al = *(const bf16x8*)&Tl[SW(ar, ac)];
            #pragma unroll
            for (int t = 0; t < 4; ++t) {
                sacc[t] = MFMA16(ah, kfh[t][s], sacc[t]);
                sacc[t] = MFMA16(ah, kfl[t][s], sacc[t]);
                sacc[t] = MFMA16(al, kfh[t][s], sacc[t]);
            }
        }

        float tmax = -1e30f;
        #pragma unroll
        for (int t = 0; t < 4; ++t)
            #pragma unroll
            for (int r = 0; r < 4; ++r) tmax = fmaxf(tmax, sacc[t][r]);
        float nm = fmaxf(m_r, tmax);
        s_r *= __expf(m_r - nm);
        float tt = 0.f;
        #pragma unroll
        for (int t = 0; t < 4; ++t)
            #pragma unroll
            for (int r = 0; r < 4; ++r) tt += __expf(sacc[t][r] - nm);
        s_r += tt;
        m_r = nm;
        __syncthreads();
    }

    float* red = (float*)sm;
    red[tid] = m_r;
    red[256 + tid] = s_r;
    __syncthreads();
    for (int off = 128; off > 0; off >>= 1) {
        if (tid < off) {
            float m2 = red[tid + off], s2 = red[256 + tid + off];
            float M = fmaxf(red[tid], m2);
            red[256 + tid] = red[256 + tid] * __expf(red[tid] - M) + s2 * __expf(m2 - M);
            red[tid] = M;
        }
        __syncthreads();
    }
    if (tid == 0) {
        pstats[((b << 7) + (hd << 4) + mt) * 2 + 0] = red[0];
        pstats[((b << 7) + (hd << 4) + mt) * 2 + 1] = red[256];
    }
}

__global__ __launch_bounds__(128)
void combine_kernel(const float* __restrict__ pstats, float* __restrict__ gstats)
{
    const int b = blockIdx.x, tid = threadIdx.x;
    __shared__ float rm[128], rs[128];
    rm[tid] = pstats[((b << 7) + tid) * 2 + 0];
    rs[tid] = pstats[((b << 7) + tid) * 2 + 1];
    __syncthreads();
    for (int off = 64; off > 0; off >>= 1) {
        if (tid < off) {
            float m2 = rm[tid + off], s2 = rs[tid + off];
            float M = fmaxf(rm[tid], m2);
            rs[tid] = rs[tid] * __expf(rm[tid] - M) + s2 * __expf(m2 - M);
            rm[tid] = M;
        }
        __syncthreads();
    }
    if (tid == 0) { gstats[b * 2] = rm[0]; gstats[b * 2 + 1] = rs[0]; }
}

__global__ __launch_bounds__(256)
void pv_kernel(const unsigned short* __restrict__ Qh, const unsigned short* __restrict__ Ql,
               const unsigned short* __restrict__ Kh, const unsigned short* __restrict__ Kl,
               const unsigned short* __restrict__ Vh, const unsigned short* __restrict__ Vl,
               const float* __restrict__ gstats, float* __restrict__ out)
{
    const int tid = threadIdx.x;
    const int mt = blockIdx.x, hd = blockIdx.y, b = blockIdx.z;
    const int mBase = mt << 6;
    const int bh = b * HEAD + hd;
    const int lane = tid & 63;
    const int w = tid >> 6;

    __shared__ __align__(16) unsigned short sm[24576];  // 48 KB
    unsigned short* Qsh = sm;
    unsigned short* Qsl = sm + 4096;
    unsigned short* Vsh = sm + 8192;
    unsigned short* Vsl = sm + 12288;
    unsigned short* Ash = sm + 16384;  // A^T tile; also K staging at start
    unsigned short* Asl = sm + 20480;

    // ---- stage K tile into A^T buffers, hoist B-fragments to registers ----
    {
        const unsigned short* kh = Kh + (((size_t)bh * NN + mBase) << 6);
        const unsigned short* kl = Kl + (((size_t)bh * NN + mBase) << 6);
        #pragma unroll
        for (int p = 0; p < 2; ++p) {
            int idx = (p << 8) + tid;
            int row = idx >> 3, c8 = (idx & 7) << 3;
            *(float4*)&Ash[SW(row, c8)] = *(const float4*)&kh[(row << 6) + c8];
            *(float4*)&Asl[SW(row, c8)] = *(const float4*)&kl[(row << 6) + c8];
        }
    }
    __syncthreads();
    bf16x8 kfh[4][2], kfl[4][2];
    {
        const int r0 = lane & 15, c0 = (lane >> 4) << 3;
        #pragma unroll
        for (int t = 0; t < 4; ++t)
            #pragma unroll
            for (int s = 0; s < 2; ++s) {
                kfh[t][s] = *(const bf16x8*)&Ash[SW(t * 16 + r0, s * 32 + c0)];
                kfl[t][s] = *(const bf16x8*)&Asl[SW(t * 16 + r0, s * 32 + c0)];
            }
    }
    __syncthreads();

    const unsigned short* qh = Qh + ((size_t)bh * NN << 6);
    const unsigned short* ql = Ql + ((size_t)bh * NN << 6);
    const unsigned short* vh = Vh + (((size_t)bh << 6) * NN);
    const unsigned short* vl = Vl + (((size_t)bh << 6) * NN);

    const float gmax = gstats[b * 2];
    const float ginv = 1.f / gstats[b * 2 + 1];

    f32x4 facc[4];
    #pragma unroll
    for (int t = 0; t < 4; ++t) facc[t] = (f32x4){0.f, 0.f, 0.f, 0.f};

    for (int nt = 0; nt < 16; ++nt) {
        const int nB = nt << 6;
        #pragma unroll
        for (int p = 0; p < 2; ++p) {
            int idx = (p << 8) + tid;
            int row = idx >> 3, c8 = (idx & 7) << 3;
            *(float4*)&Qsh[SW(row, c8)] = *(const float4*)&qh[((size_t)(nB + row) << 6) + c8];
            *(float4*)&Qsl[SW(row, c8)] = *(const float4*)&ql[((size_t)(nB + row) << 6) + c8];
            *(float4*)&Vsh[SW(row, c8)] = *(const float4*)&vh[(size_t)row * NN + nB + c8];
            *(float4*)&Vsl[SW(row, c8)] = *(const float4*)&vl[(size_t)row * NN + nB + c8];
        }
        __syncthreads();   // (1) tiles staged

        // ---- logits S[n][m], identical MFMA sequence to stats_kernel ----
        f32x4 sacc[4];
        #pragma unroll
        for (int t = 0; t < 4; ++t) sacc[t] = (f32x4){0.f, 0.f, 0.f, 0.f};
        #pragma unroll
        for (int s = 0; s < 2; ++s) {
            int ar = (w << 4) + (lane & 15);
            int ac = s * 32 + ((lane >> 4) << 3);
            bf16x8 ah = *(const bf16x8*)&Qsh[SW(ar, ac)];
            bf16x8 al = *(const bf16x8*)&Qsl[SW(ar, ac)];
            #pragma unroll
            for (int t = 0; t < 4; ++t) {
                sacc[t] = MFMA16(ah, kfh[t][s], sacc[t]);
                sacc[t] = MFMA16(ah, kfl[t][s], sacc[t]);
                sacc[t] = MFMA16(al, kfh[t][s], sacc[t]);
            }
        }

        // ---- softmax, split to bf16 hi/lo, write transposed A^T[m][n] ----
        {
            const int c0 = lane & 15;
            const int g4 = (lane >> 4) << 2;
            #pragma unroll
            for (int t = 0; t < 4; ++t) {
                union { unsigned short u[4]; uint2 v; } ph, pl;
                #pragma unroll
                for (int r = 0; r < 4; ++r) {
                    float wv = __expf(sacc[t][r] - gmax) * ginv;
                    unsigned short hh = bfh(wv);
                    ph.u[r] = hh;
                    pl.u[r] = bfh(wv - bf2f(hh));
                }
                int mrow = t * 16 + c0;          // output col j -> m
                int ncol = (w << 4) + g4;        // output row i -> n (4 consecutive)
                *(uint2*)&Ash[SW(mrow, ncol)] = ph.v;
                *(uint2*)&Asl[SW(mrow, ncol)] = pl.v;
            }
        }
        __syncthreads();   // (2) A^T written

        // ---- PV: F[m][d] += sum_n A^T[m][n] * V[d][n] ----
        #pragma unroll
        for (int s = 0; s < 2; ++s) {
            int ar = (w << 4) + (lane & 15);
            int ac = s * 32 + ((lane >> 4) << 3);
            bf16x8 pah = *(const bf16x8*)&Ash[SW(ar, ac)];
            bf16x8 pal = *(const bf16x8*)&Asl[SW(ar, ac)];
            #pragma unroll
            for (int t = 0; t < 4; ++t) {
                int vr = t * 16 + (lane & 15);
                bf16x8 vvh = *(const bf16x8*)&Vsh[SW(vr, ac)];
                bf16x8 vvl = *(const bf16x8*)&Vsl[SW(vr, ac)];
                facc[t] = MFMA16(pah, vvh, facc[t]);
                facc[t] = MFMA16(pah, vvl, facc[t]);
                facc[t] = MFMA16(pal, vvh, facc[t]);
            }
        }
        __syncthreads();   // (3) PV reads done before next stage
    }

    // ---- epilogue: stage F (fp32, [64 m][64 d]) and 2x2 avg-pool ----
    float* F = (float*)sm;   // 16 KB, reuses Qsh/Qsl region
    #pragma unroll
    for (int t = 0; t < 4; ++t) {
        int d = t * 16 + (lane & 15);
        #pragma unroll
        for (int r = 0; r < 4; ++r) {
            int m = (w << 4) + ((lane >> 4) << 2) + r;
            F[(m << 6) + d] = facc[t][r];
        }
    }
    __syncthreads();
    #pragma unroll
    for (int q = 0; q < 4; ++q) {
        int idx = (tid << 2) + q;
        int d = idx >> 4, wo = idx & 15;
        float v = 0.25f * (F[((wo << 1) << 6) + d] + F[(((wo << 1) + 1) << 6) + d] +
                           F[((32 + (wo << 1)) << 6) + d] + F[((33 + (wo << 1)) << 6) + d]);
        out[(((size_t)(b * DIMC + (hd << 6) + d) << 4) + mt) * 16 + wo] = v;
    }
}

extern "C" void kernel_launch(void* const* d_in, const int* in_sizes, int n_in,
                              void* d_out, int out_size, void* d_ws, size_t ws_size,
                              hipStream_t stream)
{
    const float* x    = (const float*)d_in[0];
    const float* wq_w = (const float*)d_in[1];
    const float* wq_b = (const float*)d_in[2];
    const float* wk_w = (const float*)d_in[3];
    const float* wk_b = (const float*)d_in[4];
    const float* wv_w = (const float*)d_in[5];
    const float* wv_b = (const float*)d_in[6];
    const float* r_h  = (const float*)d_in[7];
    const float* r_w  = (const float*)d_in[8];
    float* out = (float*)d_out;

    const size_t PRN = (size_t)BB * HEAD * NN * DH;   // 4,194,304 elems
    unsigned short* Qh = (unsigned short*)d_ws;
    unsigned short* Ql = Qh + PRN;
    unsigned short* Kh = Ql + PRN;
    unsigned short* Kl = Kh + PRN;
    unsigned short* Vh = Kl + PRN;
    unsigned short* Vl = Vh + PRN;
    float* pstats = (float*)(Vl + PRN);               // 8B-aligned (PRN even)
    float* gstats = pstats + BB * 128 * 2;

    qkv_kernel<<<dim3(128, 8, 3), 256, 0, stream>>>(x, wq_w, wq_b, wk_w, wk_b,
                                                    wv_w, wv_b, r_h, r_w,
                                                    Qh, Ql, Kh, Kl, Vh, Vl);
    stats_kernel<<<dim3(16, 8, 8), 256, 0, stream>>>(Qh, Ql, Kh, Kl, pstats);
    combine_kernel<<<dim3(8), 128, 0, stream>>>(pstats, gstats);
    pv_kernel<<<dim3(16, 8, 8), 256, 0, stream>>>(Qh, Ql, Kh, Kl, Vh, Vl, gstats, out);
}

// Round 3
// 298.602 us; speedup vs baseline: 2.1596x; 1.3423x over previous
//
#include <hip/hip_runtime.h>
#include <hip/hip_bf16.h>
#include <math.h>

// MHSA: B=8, DIM=512, H=W=32, HEAD=8, DH=64, N=1024
// Round 3: qkv projections moved to split-bf16 MFMA.
//  prep_x    : transpose+split x -> XT[b][n][c] hi/lo bf16
//  prep_w    : split W -> Wsp[z][o][c] hi/lo bf16
//  qkv_gemm  : 3-term split MFMA, 64o x 128n tile; epilogue writes
//              Q[bh][n][d], K(+R)[bh][m][d], V[bh][d][n] hi/lo (same as R2)
//  stats/combine/pv: unchanged from Round 2.
#define BB   8
#define DIMC 512
#define HEAD 8
#define DH   64
#define NN   1024
#define HW   32

typedef __attribute__((ext_vector_type(8))) __bf16 bf16x8;
typedef __attribute__((ext_vector_type(4))) float  f32x4;

#define MFMA16(a, b, c) __builtin_amdgcn_mfma_f32_16x16x32_bf16((a), (b), (c), 0, 0, 0)

// swizzled element offset in a [rows][64 bf16] LDS tile (rows = 128 B).
__device__ __forceinline__ int SW(int row, int col) {
    return (row << 6) + (col ^ ((row & 7) << 3));
}

__device__ __forceinline__ unsigned short bfh(float v) {   // fp32 -> bf16 (RNE)
    unsigned int u = __float_as_uint(v);
    return (unsigned short)((u + 0x7fffu + ((u >> 16) & 1u)) >> 16);
}
__device__ __forceinline__ float bf2f(unsigned short h) {
    return __uint_as_float(((unsigned int)h) << 16);
}

// ---------------- prep: x transpose + split ----------------
__global__ __launch_bounds__(256)
void prep_x(const float* __restrict__ x,
            unsigned short* __restrict__ XTh, unsigned short* __restrict__ XTl)
{
    const int tid = threadIdx.x;
    const int nt = blockIdx.x;     // 16
    const int ct = blockIdx.y;     // 8
    const int b  = blockIdx.z;     // 8
    const int c0 = ct << 6, n0 = nt << 6;

    __shared__ float XsT[64][68];  // [n][c]

    #pragma unroll
    for (int p = 0; p < 4; ++p) {
        int idx = tid + (p << 8);              // (cr, nc4)
        int cr = idx >> 4;
        int nc4 = (idx & 15) << 2;
        float4 v = *(const float4*)&x[((size_t)b * DIMC + c0 + cr) * NN + n0 + nc4];
        XsT[nc4 + 0][cr] = v.x;
        XsT[nc4 + 1][cr] = v.y;
        XsT[nc4 + 2][cr] = v.z;
        XsT[nc4 + 3][cr] = v.w;
    }
    __syncthreads();
    #pragma unroll
    for (int p = 0; p < 4; ++p) {
        int idx = tid + (p << 8);
        int n = idx >> 4;
        int c4 = (idx & 15) << 2;
        float4 v = *(const float4*)&XsT[n][c4];
        float vv[4] = {v.x, v.y, v.z, v.w};
        union { unsigned short u[4]; uint2 w; } ph, pl;
        #pragma unroll
        for (int j = 0; j < 4; ++j) {
            unsigned short hh = bfh(vv[j]);
            ph.u[j] = hh;
            pl.u[j] = bfh(vv[j] - bf2f(hh));
        }
        size_t off = ((size_t)(b * NN + n0 + n)) * DIMC + c0 + c4;
        *(uint2*)&XTh[off] = ph.w;
        *(uint2*)&XTl[off] = pl.w;
    }
}

// ---------------- prep: weight split ----------------
__global__ __launch_bounds__(256)
void prep_w(const float* __restrict__ wq, const float* __restrict__ wk,
            const float* __restrict__ wv,
            unsigned short* __restrict__ Wh, unsigned short* __restrict__ Wl)
{
    const int z = blockIdx.y;
    const float* src = (z == 0) ? wq : (z == 1) ? wk : wv;
    const size_t zb = (size_t)z * DIMC * DIMC;
    #pragma unroll
    for (int p = 0; p < 4; ++p) {
        size_t i = (size_t)blockIdx.x * 4096 + (p << 10) + (threadIdx.x << 2);
        float4 v = *(const float4*)&src[i];
        float vv[4] = {v.x, v.y, v.z, v.w};
        union { unsigned short u[4]; uint2 w; } ph, pl;
        #pragma unroll
        for (int j = 0; j < 4; ++j) {
            unsigned short hh = bfh(vv[j]);
            ph.u[j] = hh;
            pl.u[j] = bfh(vv[j] - bf2f(hh));
        }
        *(uint2*)&Wh[zb + i] = ph.w;
        *(uint2*)&Wl[zb + i] = pl.w;
    }
}

// ---------------- qkv GEMM (MFMA) ----------------
__global__ __launch_bounds__(256)
void qkv_gemm(const unsigned short* __restrict__ XTh, const unsigned short* __restrict__ XTl,
              const unsigned short* __restrict__ Wh, const unsigned short* __restrict__ Wl,
              const float* __restrict__ wq_b, const float* __restrict__ wk_b,
              const float* __restrict__ wv_b,
              const float* __restrict__ r_h, const float* __restrict__ r_w,
              unsigned short* __restrict__ Qh, unsigned short* __restrict__ Ql,
              unsigned short* __restrict__ Kh, unsigned short* __restrict__ Kl,
              unsigned short* __restrict__ Vh, unsigned short* __restrict__ Vl)
{
    const int tid = threadIdx.x;
    const int z = blockIdx.z, hd = blockIdx.y;
    const int gn = blockIdx.x << 7;            // global n over B*N, step 128
    const int b = gn >> 10, posb = gn & 1023;
    const int oB = hd << 6;
    const int lane = tid & 63, w = tid >> 6;

    __shared__ __align__(16) unsigned short sm[24576];  // 48 KB
    unsigned short* Ah = sm;              // W tile [64][64]
    unsigned short* Al = sm + 4096;
    unsigned short* Bh = sm + 8192;       // XT tile [128][64]
    unsigned short* Bl = sm + 16384;

    const float* bias = (z == 0) ? wq_b : (z == 1) ? wk_b : wv_b;
    const unsigned short* wsh = Wh + (size_t)z * DIMC * DIMC + (size_t)oB * DIMC;
    const unsigned short* wsl = Wl + (size_t)z * DIMC * DIMC + (size_t)oB * DIMC;
    const unsigned short* xth = XTh + ((size_t)(b * NN + posb)) * DIMC;
    const unsigned short* xtl = XTl + ((size_t)(b * NN + posb)) * DIMC;

    f32x4 acc[8];
    #pragma unroll
    for (int t = 0; t < 8; ++t) acc[t] = (f32x4){0.f, 0.f, 0.f, 0.f};

    for (int ks = 0; ks < 8; ++ks) {
        const int c0 = ks << 6;
        #pragma unroll
        for (int p = 0; p < 2; ++p) {          // A: 64x64 hi/lo
            int idx = (p << 8) + tid;
            int row = idx >> 3, col8 = (idx & 7) << 3;
            size_t g = (size_t)row * DIMC + c0 + col8;
            *(float4*)&Ah[SW(row, col8)] = *(const float4*)&wsh[g];
            *(float4*)&Al[SW(row, col8)] = *(const float4*)&wsl[g];
        }
        #pragma unroll
        for (int p = 0; p < 4; ++p) {          // B: 128x64 hi/lo
            int idx = (p << 8) + tid;
            int row = idx >> 3, col8 = (idx & 7) << 3;
            size_t g = (size_t)row * DIMC + c0 + col8;
            *(float4*)&Bh[SW(row, col8)] = *(const float4*)&xth[g];
            *(float4*)&Bl[SW(row, col8)] = *(const float4*)&xtl[g];
        }
        __syncthreads();

        const int ar = (w << 4) + (lane & 15);
        const int kc = (lane >> 4) << 3;
        bf16x8 ah[2], al[2];
        ah[0] = *(const bf16x8*)&Ah[SW(ar, kc)];
        ah[1] = *(const bf16x8*)&Ah[SW(ar, 32 + kc)];
        al[0] = *(const bf16x8*)&Al[SW(ar, kc)];
        al[1] = *(const bf16x8*)&Al[SW(ar, 32 + kc)];
        #pragma unroll
        for (int t = 0; t < 8; ++t) {
            int br = (t << 4) + (lane & 15);
            #pragma unroll
            for (int s = 0; s < 2; ++s) {
                bf16x8 xh = *(const bf16x8*)&Bh[SW(br, s * 32 + kc)];
                bf16x8 xl = *(const bf16x8*)&Bl[SW(br, s * 32 + kc)];
                acc[t] = MFMA16(ah[s], xh, acc[t]);
                acc[t] = MFMA16(ah[s], xl, acc[t]);
                acc[t] = MFMA16(al[s], xh, acc[t]);
            }
        }
        __syncthreads();
    }

    // ---- epilogue: stage fp32 tile [64 o][128 n] in LDS ----
    float* F = (float*)sm;    // [64][132] = 33.8 KB
    #pragma unroll
    for (int t = 0; t < 8; ++t) {
        int n = (t << 4) + (lane & 15);
        #pragma unroll
        for (int r = 0; r < 4; ++r) {
            int o = (w << 4) + ((lane >> 4) << 2) + r;
            F[o * 132 + n] = acc[t][r];
        }
    }
    __syncthreads();

    const size_t bh = (size_t)(b * HEAD + hd);
    if (z != 2) {
        unsigned short* Dh = (z == 0) ? Qh : Kh;
        unsigned short* Dl = (z == 0) ? Ql : Kl;
        #pragma unroll
        for (int p = 0; p < 8; ++p) {
            int idx = (p << 8) + tid;          // 2048 = 128 n x 16 d-quads
            int n = idx >> 4, d0 = (idx & 15) << 2;
            union { unsigned short u[4]; uint2 v; } ph, pl;
            #pragma unroll
            for (int i = 0; i < 4; ++i) {
                int d = d0 + i;
                float val = F[d * 132 + n] + bias[oB + d];
                if (z == 1) {
                    int m = posb + n;
                    val += r_h[(size_t)(oB + d) * HW + (m & 31)]
                         + r_w[(size_t)(oB + d) * HW + (m >> 5)];
                }
                unsigned short hh = bfh(val);
                ph.u[i] = hh;
                pl.u[i] = bfh(val - bf2f(hh));
            }
            size_t off = (((size_t)bh * NN + posb + n) << 6) + d0;
            *(uint2*)&Dh[off] = ph.v;
            *(uint2*)&Dl[off] = pl.v;
        }
    } else {
        #pragma unroll
        for (int p = 0; p < 8; ++p) {
            int idx = (p << 8) + tid;          // 2048 = 64 d x 32 n-quads
            int d = idx >> 5, n0 = (idx & 31) << 2;
            float4 v = *(const float4*)&F[d * 132 + n0];
            float vv[4] = {v.x, v.y, v.z, v.w};
            float bia = bias[oB + d];
            union { unsigned short u[4]; uint2 w2; } ph, pl;
            #pragma unroll
            for (int j = 0; j < 4; ++j) {
                float val = vv[j] + bia;
                unsigned short hh = bfh(val);
                ph.u[j] = hh;
                pl.u[j] = bfh(val - bf2f(hh));
            }
            size_t off = (((size_t)bh << 6) + d) * NN + posb + n0;
            *(uint2*)&Vh[off] = ph.w2;
            *(uint2*)&Vl[off] = pl.w2;
        }
    }
}

// ---------------- stats / combine / pv (unchanged from R2) ----------------
__global__ __launch_bounds__(256)
void stats_kernel(const unsigned short* __restrict__ Qh, const unsigned short* __restrict__ Ql,
                  const unsigned short* __restrict__ Kh, const unsigned short* __restrict__ Kl,
                  float* __restrict__ pstats)
{
    const int tid = threadIdx.x;
    const int mt = blockIdx.x, hd = blockIdx.y, b = blockIdx.z;
    const int mBase = mt << 6;
    const int bh = b * HEAD + hd;
    const int lane = tid & 63;
    const int w = tid >> 6;

    __shared__ __align__(16) unsigned short sm[8192];
    unsigned short* Th = sm;
    unsigned short* Tl = sm + 4096;

    {
        const unsigned short* kh = Kh + (((size_t)bh * NN + mBase) << 6);
        const unsigned short* kl = Kl + (((size_t)bh * NN + mBase) << 6);
        #pragma unroll
        for (int p = 0; p < 2; ++p) {
            int idx = (p << 8) + tid;
            int row = idx >> 3, c8 = (idx & 7) << 3;
            *(float4*)&Th[SW(row, c8)] = *(const float4*)&kh[(row << 6) + c8];
            *(float4*)&Tl[SW(row, c8)] = *(const float4*)&kl[(row << 6) + c8];
        }
    }
    __syncthreads();
    bf16x8 kfh[4][2], kfl[4][2];
    {
        const int r0 = lane & 15, c0 = (lane >> 4) << 3;
        #pragma unroll
        for (int t = 0; t < 4; ++t)
            #pragma unroll
            for (int s = 0; s < 2; ++s) {
                kfh[t][s] = *(const bf16x8*)&Th[SW(t * 16 + r0, s * 32 + c0)];
                kfl[t][s] = *(const bf16x8*)&Tl[SW(t * 16 + r0, s * 32 + c0)];
            }
    }
    __syncthreads();

    const unsigned short* qh = Qh + ((size_t)bh * NN << 6);
    const unsigned short* ql = Ql + ((size_t)bh * NN << 6);

    float m_r = -1e30f, s_r = 0.f;

    for (int nt = 0; nt < 16; ++nt) {
        const int nB = nt << 6;
        #pragma unroll
        for (int p = 0; p < 2; ++p) {
            int idx = (p << 8) + tid;
            int row = idx >> 3, c8 = (idx & 7) << 3;
            *(float4*)&Th[SW(row, c8)] = *(const float4*)&qh[((size_t)(nB + row) << 6) + c8];
            *(float4*)&Tl[SW(row, c8)] = *(const float4*)&ql[((size_t)(nB + row) << 6) + c8];
        }
        __syncthreads();

        f32x4 sacc[4];
        #pragma unroll
        for (int t = 0; t < 4; ++t) sacc[t] = (f32x4){0.f, 0.f, 0.f, 0.f};

        #pragma unroll
        for (int s = 0; s < 2; ++s) {
            int ar = (w << 4) + (lane & 15);
            int ac = s * 32 + ((lane >> 4) << 3);
            bf16x8 ah = *(const bf16x8*)&Th[SW(ar, ac)];
            bf16x8 al = *(const bf16x8*)&Tl[SW(ar, ac)];
            #pragma unroll
            for (int t = 0; t < 4; ++t) {
                sacc[t] = MFMA16(ah, kfh[t][s], sacc[t]);
                sacc[t] = MFMA16(ah, kfl[t][s], sacc[t]);
                sacc[t] = MFMA16(al, kfh[t][s], sacc[t]);
            }
        }

        float tmax = -1e30f;
        #pragma unroll
        for (int t = 0; t < 4; ++t)
            #pragma unroll
            for (int r = 0; r < 4; ++r) tmax = fmaxf(tmax, sacc[t][r]);
        float nm = fmaxf(m_r, tmax);
        s_r *= __expf(m_r - nm);
        float tt = 0.f;
        #pragma unroll
        for (int t = 0; t < 4; ++t)
            #pragma unroll
            for (int r = 0; r < 4; ++r) tt += __expf(sacc[t][r] - nm);
        s_r += tt;
        m_r = nm;
        __syncthreads();
    }

    float* red = (float*)sm;
    red[tid] = m_r;
    red[256 + tid] = s_r;
    __syncthreads();
    for (int off = 128; off > 0; off >>= 1) {
        if (tid < off) {
            float m2 = red[tid + off], s2 = red[256 + tid + off];
            float M = fmaxf(red[tid], m2);
            red[256 + tid] = red[256 + tid] * __expf(red[tid] - M) + s2 * __expf(m2 - M);
            red[tid] = M;
        }
        __syncthreads();
    }
    if (tid == 0) {
        pstats[((b << 7) + (hd << 4) + mt) * 2 + 0] = red[0];
        pstats[((b << 7) + (hd << 4) + mt) * 2 + 1] = red[256];
    }
}

__global__ __launch_bounds__(128)
void combine_kernel(const float* __restrict__ pstats, float* __restrict__ gstats)
{
    const int b = blockIdx.x, tid = threadIdx.x;
    __shared__ float rm[128], rs[128];
    rm[tid] = pstats[((b << 7) + tid) * 2 + 0];
    rs[tid] = pstats[((b << 7) + tid) * 2 + 1];
    __syncthreads();
    for (int off = 64; off > 0; off >>= 1) {
        if (tid < off) {
            float m2 = rm[tid + off], s2 = rs[tid + off];
            float M = fmaxf(rm[tid], m2);
            rs[tid] = rs[tid] * __expf(rm[tid] - M) + s2 * __expf(m2 - M);
            rm[tid] = M;
        }
        __syncthreads();
    }
    if (tid == 0) { gstats[b * 2] = rm[0]; gstats[b * 2 + 1] = rs[0]; }
}

__global__ __launch_bounds__(256)
void pv_kernel(const unsigned short* __restrict__ Qh, const unsigned short* __restrict__ Ql,
               const unsigned short* __restrict__ Kh, const unsigned short* __restrict__ Kl,
               const unsigned short* __restrict__ Vh, const unsigned short* __restrict__ Vl,
               const float* __restrict__ gstats, float* __restrict__ out)
{
    const int tid = threadIdx.x;
    const int mt = blockIdx.x, hd = blockIdx.y, b = blockIdx.z;
    const int mBase = mt << 6;
    const int bh = b * HEAD + hd;
    const int lane = tid & 63;
    const int w = tid >> 6;

    __shared__ __align__(16) unsigned short sm[24576];
    unsigned short* Qsh = sm;
    unsigned short* Qsl = sm + 4096;
    unsigned short* Vsh = sm + 8192;
    unsigned short* Vsl = sm + 12288;
    unsigned short* Ash = sm + 16384;
    unsigned short* Asl = sm + 20480;

    {
        const unsigned short* kh = Kh + (((size_t)bh * NN + mBase) << 6);
        const unsigned short* kl = Kl + (((size_t)bh * NN + mBase) << 6);
        #pragma unroll
        for (int p = 0; p < 2; ++p) {
            int idx = (p << 8) + tid;
            int row = idx >> 3, c8 = (idx & 7) << 3;
            *(float4*)&Ash[SW(row, c8)] = *(const float4*)&kh[(row << 6) + c8];
            *(float4*)&Asl[SW(row, c8)] = *(const float4*)&kl[(row << 6) + c8];
        }
    }
    __syncthreads();
    bf16x8 kfh[4][2], kfl[4][2];
    {
        const int r0 = lane & 15, c0 = (lane >> 4) << 3;
        #pragma unroll
        for (int t = 0; t < 4; ++t)
            #pragma unroll
            for (int s = 0; s < 2; ++s) {
                kfh[t][s] = *(const bf16x8*)&Ash[SW(t * 16 + r0, s * 32 + c0)];
                kfl[t][s] = *(const bf16x8*)&Asl[SW(t * 16 + r0, s * 32 + c0)];
            }
    }
    __syncthreads();

    const unsigned short* qh = Qh + ((size_t)bh * NN << 6);
    const unsigned short* ql = Ql + ((size_t)bh * NN << 6);
    const unsigned short* vh = Vh + (((size_t)bh << 6) * NN);
    const unsigned short* vl = Vl + (((size_t)bh << 6) * NN);

    const float gmax = gstats[b * 2];
    const float ginv = 1.f / gstats[b * 2 + 1];

    f32x4 facc[4];
    #pragma unroll
    for (int t = 0; t < 4; ++t) facc[t] = (f32x4){0.f, 0.f, 0.f, 0.f};

    for (int nt = 0; nt < 16; ++nt) {
        const int nB = nt << 6;
        #pragma unroll
        for (int p = 0; p < 2; ++p) {
            int idx = (p << 8) + tid;
            int row = idx >> 3, c8 = (idx & 7) << 3;
            *(float4*)&Qsh[SW(row, c8)] = *(const float4*)&qh[((size_t)(nB + row) << 6) + c8];
            *(float4*)&Qsl[SW(row, c8)] = *(const float4*)&ql[((size_t)(nB + row) << 6) + c8];
            *(float4*)&Vsh[SW(row, c8)] = *(const float4*)&vh[(size_t)row * NN + nB + c8];
            *(float4*)&Vsl[SW(row, c8)] = *(const float4*)&vl[(size_t)row * NN + nB + c8];
        }
        __syncthreads();

        f32x4 sacc[4];
        #pragma unroll
        for (int t = 0; t < 4; ++t) sacc[t] = (f32x4){0.f, 0.f, 0.f, 0.f};
        #pragma unroll
        for (int s = 0; s < 2; ++s) {
            int ar = (w << 4) + (lane & 15);
            int ac = s * 32 + ((lane >> 4) << 3);
            bf16x8 ah = *(const bf16x8*)&Qsh[SW(ar, ac)];
            bf16x8 al = *(const bf16x8*)&Qsl[SW(ar, ac)];
            #pragma unroll
            for (int t = 0; t < 4; ++t) {
                sacc[t] = MFMA16(ah, kfh[t][s], sacc[t]);
                sacc[t] = MFMA16(ah, kfl[t][s], sacc[t]);
                sacc[t] = MFMA16(al, kfh[t][s], sacc[t]);
            }
        }

        {
            const int c0 = lane & 15;
            const int g4 = (lane >> 4) << 2;
            #pragma unroll
            for (int t = 0; t < 4; ++t) {
                union { unsigned short u[4]; uint2 v; } ph, pl;
                #pragma unroll
                for (int r = 0; r < 4; ++r) {
                    float wv = __expf(sacc[t][r] - gmax) * ginv;
                    unsigned short hh = bfh(wv);
                    ph.u[r] = hh;
                    pl.u[r] = bfh(wv - bf2f(hh));
                }
                int mrow = t * 16 + c0;
                int ncol = (w << 4) + g4;
                *(uint2*)&Ash[SW(mrow, ncol)] = ph.v;
                *(uint2*)&Asl[SW(mrow, ncol)] = pl.v;
            }
        }
        __syncthreads();

        #pragma unroll
        for (int s = 0; s < 2; ++s) {
            int ar = (w << 4) + (lane & 15);
            int ac = s * 32 + ((lane >> 4) << 3);
            bf16x8 pah = *(const bf16x8*)&Ash[SW(ar, ac)];
            bf16x8 pal = *(const bf16x8*)&Asl[SW(ar, ac)];
            #pragma unroll
            for (int t = 0; t < 4; ++t) {
                int vr = t * 16 + (lane & 15);
                bf16x8 vvh = *(const bf16x8*)&Vsh[SW(vr, ac)];
                bf16x8 vvl = *(const bf16x8*)&Vsl[SW(vr, ac)];
                facc[t] = MFMA16(pah, vvh, facc[t]);
                facc[t] = MFMA16(pah, vvl, facc[t]);
                facc[t] = MFMA16(pal, vvh, facc[t]);
            }
        }
        __syncthreads();
    }

    float* F = (float*)sm;
    #pragma unroll
    for (int t = 0; t < 4; ++t) {
        int d = t * 16 + (lane & 15);
        #pragma unroll
        for (int r = 0; r < 4; ++r) {
            int m = (w << 4) + ((lane >> 4) << 2) + r;
            F[(m << 6) + d] = facc[t][r];
        }
    }
    __syncthreads();
    #pragma unroll
    for (int q = 0; q < 4; ++q) {
        int idx = (tid << 2) + q;
        int d = idx >> 4, wo = idx & 15;
        float v = 0.25f * (F[((wo << 1) << 6) + d] + F[(((wo << 1) + 1) << 6) + d] +
                           F[((32 + (wo << 1)) << 6) + d] + F[((33 + (wo << 1)) << 6) + d]);
        out[(((size_t)(b * DIMC + (hd << 6) + d) << 4) + mt) * 16 + wo] = v;
    }
}

extern "C" void kernel_launch(void* const* d_in, const int* in_sizes, int n_in,
                              void* d_out, int out_size, void* d_ws, size_t ws_size,
                              hipStream_t stream)
{
    const float* x    = (const float*)d_in[0];
    const float* wq_w = (const float*)d_in[1];
    const float* wq_b = (const float*)d_in[2];
    const float* wk_w = (const float*)d_in[3];
    const float* wk_b = (const float*)d_in[4];
    const float* wv_w = (const float*)d_in[5];
    const float* wv_b = (const float*)d_in[6];
    const float* r_h  = (const float*)d_in[7];
    const float* r_w  = (const float*)d_in[8];
    float* out = (float*)d_out;

    const size_t PRN = (size_t)BB * HEAD * NN * DH;   // 4,194,304 elems
    const size_t WSZ = (size_t)3 * DIMC * DIMC;       //   786,432 elems
    unsigned short* Qh  = (unsigned short*)d_ws;
    unsigned short* Ql  = Qh + PRN;
    unsigned short* Kh  = Ql + PRN;
    unsigned short* Kl  = Kh + PRN;
    unsigned short* Vh  = Kl + PRN;
    unsigned short* Vl  = Vh + PRN;
    unsigned short* XTh = Vl + PRN;
    unsigned short* XTl = XTh + PRN;
    unsigned short* Wh  = XTl + PRN;
    unsigned short* Wl  = Wh + WSZ;
    float* pstats = (float*)(Wl + WSZ);
    float* gstats = pstats + BB * 128 * 2;

    prep_x<<<dim3(16, 8, 8), 256, 0, stream>>>(x, XTh, XTl);
    prep_w<<<dim3(64, 3), 256, 0, stream>>>(wq_w, wk_w, wv_w, Wh, Wl);
    qkv_gemm<<<dim3(64, 8, 3), 256, 0, stream>>>(XTh, XTl, Wh, Wl,
                                                 wq_b, wk_b, wv_b, r_h, r_w,
                                                 Qh, Ql, Kh, Kl, Vh, Vl);
    stats_kernel<<<dim3(16, 8, 8), 256, 0, stream>>>(Qh, Ql, Kh, Kl, pstats);
    combine_kernel<<<dim3(8), 128, 0, stream>>>(pstats, gstats);
    pv_kernel<<<dim3(16, 8, 8), 256, 0, stream>>>(Qh, Ql, Kh, Kl, Vh, Vl, gstats, out);
}

// Round 6
// 256.938 us; speedup vs baseline: 2.5098x; 1.1622x over previous
//
#include <hip/hip_runtime.h>
#include <hip/hip_bf16.h>
#include <math.h>

// MHSA: B=8, DIM=512, H=W=32, HEAD=8, DH=64, N=1024
// Round 4 (2nd resubmit; R4/R5 benches were broker timeouts): register-resident attention.
//  - stats: K frags + Q frags loaded global->reg; NO LDS, NO barriers in loop.
//  - pv:    QK^T C-layout == B-layout of K=16 MFMA -> softmax stays in
//           registers and feeds PV directly (no A^T LDS round-trip).
//           Each wave owns 16 n per tile, accumulates partial F^T[d][m];
//           cross-wave reduce once per block. V (only) staged in LDS.
#define BB   8
#define DIMC 512
#define HEAD 8
#define DH   64
#define NN   1024
#define HW   32

typedef __attribute__((ext_vector_type(8))) __bf16 bf16x8;
typedef __attribute__((ext_vector_type(4))) float  f32x4;
typedef __attribute__((ext_vector_type(4))) short  short4v;

#define MFMA16(a, b, c) __builtin_amdgcn_mfma_f32_16x16x32_bf16((a), (b), (c), 0, 0, 0)

__device__ __forceinline__ f32x4 mfma_pv(short4v a, short4v b, f32x4 c) {
#if __has_builtin(__builtin_amdgcn_mfma_f32_16x16x16bf16_1k)
    return __builtin_amdgcn_mfma_f32_16x16x16bf16_1k(a, b, c, 0, 0, 0);
#else
    asm volatile("v_mfma_f32_16x16x16_bf16 %0, %1, %2, %0"
                 : "+v"(c) : "v"(a), "v"(b));
    return c;
#endif
}

// swizzled element offset in a [rows][64 bf16] LDS tile (rows = 128 B).
__device__ __forceinline__ int SW(int row, int col) {
    return (row << 6) + (col ^ ((row & 7) << 3));
}

__device__ __forceinline__ unsigned short bfh(float v) {   // fp32 -> bf16 (RNE)
    unsigned int u = __float_as_uint(v);
    return (unsigned short)((u + 0x7fffu + ((u >> 16) & 1u)) >> 16);
}
__device__ __forceinline__ float bf2f(unsigned short h) {
    return __uint_as_float(((unsigned int)h) << 16);
}

// ---------------- prep: x transpose + split ----------------
__global__ __launch_bounds__(256)
void prep_x(const float* __restrict__ x,
            unsigned short* __restrict__ XTh, unsigned short* __restrict__ XTl)
{
    const int tid = threadIdx.x;
    const int nt = blockIdx.x;     // 16
    const int ct = blockIdx.y;     // 8
    const int b  = blockIdx.z;     // 8
    const int c0 = ct << 6, n0 = nt << 6;

    __shared__ float XsT[64][68];  // [n][c]

    #pragma unroll
    for (int p = 0; p < 4; ++p) {
        int idx = tid + (p << 8);
        int cr = idx >> 4;
        int nc4 = (idx & 15) << 2;
        float4 v = *(const float4*)&x[((size_t)b * DIMC + c0 + cr) * NN + n0 + nc4];
        XsT[nc4 + 0][cr] = v.x;
        XsT[nc4 + 1][cr] = v.y;
        XsT[nc4 + 2][cr] = v.z;
        XsT[nc4 + 3][cr] = v.w;
    }
    __syncthreads();
    #pragma unroll
    for (int p = 0; p < 4; ++p) {
        int idx = tid + (p << 8);
        int n = idx >> 4;
        int c4 = (idx & 15) << 2;
        float4 v = *(const float4*)&XsT[n][c4];
        float vv[4] = {v.x, v.y, v.z, v.w};
        union { unsigned short u[4]; uint2 w; } ph, pl;
        #pragma unroll
        for (int j = 0; j < 4; ++j) {
            unsigned short hh = bfh(vv[j]);
            ph.u[j] = hh;
            pl.u[j] = bfh(vv[j] - bf2f(hh));
        }
        size_t off = ((size_t)(b * NN + n0 + n)) * DIMC + c0 + c4;
        *(uint2*)&XTh[off] = ph.w;
        *(uint2*)&XTl[off] = pl.w;
    }
}

// ---------------- prep: weight split ----------------
__global__ __launch_bounds__(256)
void prep_w(const float* __restrict__ wq, const float* __restrict__ wk,
            const float* __restrict__ wv,
            unsigned short* __restrict__ Wh, unsigned short* __restrict__ Wl)
{
    const int z = blockIdx.y;
    const float* src = (z == 0) ? wq : (z == 1) ? wk : wv;
    const size_t zb = (size_t)z * DIMC * DIMC;
    #pragma unroll
    for (int p = 0; p < 4; ++p) {
        size_t i = (size_t)blockIdx.x * 4096 + (p << 10) + (threadIdx.x << 2);
        float4 v = *(const float4*)&src[i];
        float vv[4] = {v.x, v.y, v.z, v.w};
        union { unsigned short u[4]; uint2 w; } ph, pl;
        #pragma unroll
        for (int j = 0; j < 4; ++j) {
            unsigned short hh = bfh(vv[j]);
            ph.u[j] = hh;
            pl.u[j] = bfh(vv[j] - bf2f(hh));
        }
        *(uint2*)&Wh[zb + i] = ph.w;
        *(uint2*)&Wl[zb + i] = pl.w;
    }
}

// ---------------- qkv GEMM (MFMA) ----------------
__global__ __launch_bounds__(256)
void qkv_gemm(const unsigned short* __restrict__ XTh, const unsigned short* __restrict__ XTl,
              const unsigned short* __restrict__ Wh, const unsigned short* __restrict__ Wl,
              const float* __restrict__ wq_b, const float* __restrict__ wk_b,
              const float* __restrict__ wv_b,
              const float* __restrict__ r_h, const float* __restrict__ r_w,
              unsigned short* __restrict__ Qh, unsigned short* __restrict__ Ql,
              unsigned short* __restrict__ Kh, unsigned short* __restrict__ Kl,
              unsigned short* __restrict__ Vh, unsigned short* __restrict__ Vl)
{
    const int tid = threadIdx.x;
    const int z = blockIdx.z, hd = blockIdx.y;
    const int gn = blockIdx.x << 7;
    const int b = gn >> 10, posb = gn & 1023;
    const int oB = hd << 6;
    const int lane = tid & 63, w = tid >> 6;

    __shared__ __align__(16) unsigned short sm[24576];  // 48 KB
    unsigned short* Ah = sm;
    unsigned short* Al = sm + 4096;
    unsigned short* Bh = sm + 8192;
    unsigned short* Bl = sm + 16384;

    const float* bias = (z == 0) ? wq_b : (z == 1) ? wk_b : wv_b;
    const unsigned short* wsh = Wh + (size_t)z * DIMC * DIMC + (size_t)oB * DIMC;
    const unsigned short* wsl = Wl + (size_t)z * DIMC * DIMC + (size_t)oB * DIMC;
    const unsigned short* xth = XTh + ((size_t)(b * NN + posb)) * DIMC;
    const unsigned short* xtl = XTl + ((size_t)(b * NN + posb)) * DIMC;

    f32x4 acc[8];
    #pragma unroll
    for (int t = 0; t < 8; ++t) acc[t] = (f32x4){0.f, 0.f, 0.f, 0.f};

    for (int ks = 0; ks < 8; ++ks) {
        const int c0 = ks << 6;
        #pragma unroll
        for (int p = 0; p < 2; ++p) {
            int idx = (p << 8) + tid;
            int row = idx >> 3, col8 = (idx & 7) << 3;
            size_t g = (size_t)row * DIMC + c0 + col8;
            *(float4*)&Ah[SW(row, col8)] = *(const float4*)&wsh[g];
            *(float4*)&Al[SW(row, col8)] = *(const float4*)&wsl[g];
        }
        #pragma unroll
        for (int p = 0; p < 4; ++p) {
            int idx = (p << 8) + tid;
            int row = idx >> 3, col8 = (idx & 7) << 3;
            size_t g = (size_t)row * DIMC + c0 + col8;
            *(float4*)&Bh[SW(row, col8)] = *(const float4*)&xth[g];
            *(float4*)&Bl[SW(row, col8)] = *(const float4*)&xtl[g];
        }
        __syncthreads();

        const int ar = (w << 4) + (lane & 15);
        const int kc = (lane >> 4) << 3;
        bf16x8 ah[2], al[2];
        ah[0] = *(const bf16x8*)&Ah[SW(ar, kc)];
        ah[1] = *(const bf16x8*)&Ah[SW(ar, 32 + kc)];
        al[0] = *(const bf16x8*)&Al[SW(ar, kc)];
        al[1] = *(const bf16x8*)&Al[SW(ar, 32 + kc)];
        #pragma unroll
        for (int t = 0; t < 8; ++t) {
            int br = (t << 4) + (lane & 15);
            #pragma unroll
            for (int s = 0; s < 2; ++s) {
                bf16x8 xh = *(const bf16x8*)&Bh[SW(br, s * 32 + kc)];
                bf16x8 xl = *(const bf16x8*)&Bl[SW(br, s * 32 + kc)];
                acc[t] = MFMA16(ah[s], xh, acc[t]);
                acc[t] = MFMA16(ah[s], xl, acc[t]);
                acc[t] = MFMA16(al[s], xh, acc[t]);
            }
        }
        __syncthreads();
    }

    float* F = (float*)sm;    // [64][132]
    #pragma unroll
    for (int t = 0; t < 8; ++t) {
        int n = (t << 4) + (lane & 15);
        #pragma unroll
        for (int r = 0; r < 4; ++r) {
            int o = (w << 4) + ((lane >> 4) << 2) + r;
            F[o * 132 + n] = acc[t][r];
        }
    }
    __syncthreads();

    const size_t bh = (size_t)(b * HEAD + hd);
    if (z != 2) {
        unsigned short* Dh = (z == 0) ? Qh : Kh;
        unsigned short* Dl = (z == 0) ? Ql : Kl;
        #pragma unroll
        for (int p = 0; p < 8; ++p) {
            int idx = (p << 8) + tid;
            int n = idx >> 4, d0 = (idx & 15) << 2;
            union { unsigned short u[4]; uint2 v; } ph, pl;
            #pragma unroll
            for (int i = 0; i < 4; ++i) {
                int d = d0 + i;
                float val = F[d * 132 + n] + bias[oB + d];
                if (z == 1) {
                    int m = posb + n;
                    val += r_h[(size_t)(oB + d) * HW + (m & 31)]
                         + r_w[(size_t)(oB + d) * HW + (m >> 5)];
                }
                unsigned short hh = bfh(val);
                ph.u[i] = hh;
                pl.u[i] = bfh(val - bf2f(hh));
            }
            size_t off = (((size_t)bh * NN + posb + n) << 6) + d0;
            *(uint2*)&Dh[off] = ph.v;
            *(uint2*)&Dl[off] = pl.v;
        }
    } else {
        #pragma unroll
        for (int p = 0; p < 8; ++p) {
            int idx = (p << 8) + tid;
            int d = idx >> 5, n0 = (idx & 31) << 2;
            float4 v = *(const float4*)&F[d * 132 + n0];
            float vv[4] = {v.x, v.y, v.z, v.w};
            float bia = bias[oB + d];
            union { unsigned short u[4]; uint2 w2; } ph, pl;
            #pragma unroll
            for (int j = 0; j < 4; ++j) {
                float val = vv[j] + bia;
                unsigned short hh = bfh(val);
                ph.u[j] = hh;
                pl.u[j] = bfh(val - bf2f(hh));
            }
            size_t off = (((size_t)bh << 6) + d) * NN + posb + n0;
            *(uint2*)&Vh[off] = ph.w2;
            *(uint2*)&Vl[off] = pl.w2;
        }
    }
}

// ---------------- stats: no LDS, no barriers in loop ----------------
__global__ __launch_bounds__(256, 4)
void stats_kernel(const unsigned short* __restrict__ Qh, const unsigned short* __restrict__ Ql,
                  const unsigned short* __restrict__ Kh, const unsigned short* __restrict__ Kl,
                  float* __restrict__ pstats)
{
    const int tid = threadIdx.x;
    const int mt = blockIdx.x, hd = blockIdx.y, b = blockIdx.z;
    const int bh = b * HEAD + hd;
    const int lane = tid & 63, w = tid >> 6;
    const int r0 = lane & 15, c0 = (lane >> 4) << 3;

    __shared__ float red[512];

    // K fragments: global -> reg, once
    const unsigned short* kh = Kh + (((size_t)bh * NN + (mt << 6)) << 6);
    const unsigned short* kl = Kl + (((size_t)bh * NN + (mt << 6)) << 6);
    bf16x8 kfh[4][2], kfl[4][2];
    #pragma unroll
    for (int t = 0; t < 4; ++t)
        #pragma unroll
        for (int s = 0; s < 2; ++s) {
            int off = (((t << 4) + r0) << 6) + (s << 5) + c0;
            kfh[t][s] = *(const bf16x8*)&kh[off];
            kfl[t][s] = *(const bf16x8*)&kl[off];
        }

    const unsigned short* qh = Qh + (((size_t)bh * NN) << 6);
    const unsigned short* ql = Ql + (((size_t)bh * NN) << 6);

    float m_r = -1e30f, s_r = 0.f;

    for (int nt = 0; nt < 16; ++nt) {
        const int qrow = (nt << 6) + (w << 4) + r0;
        const size_t qb = ((size_t)qrow << 6) + c0;
        bf16x8 ah0 = *(const bf16x8*)&qh[qb];
        bf16x8 ah1 = *(const bf16x8*)&qh[qb + 32];
        bf16x8 al0 = *(const bf16x8*)&ql[qb];
        bf16x8 al1 = *(const bf16x8*)&ql[qb + 32];

        f32x4 sacc[4];
        #pragma unroll
        for (int t = 0; t < 4; ++t) sacc[t] = (f32x4){0.f, 0.f, 0.f, 0.f};
        #pragma unroll
        for (int t = 0; t < 4; ++t) {
            sacc[t] = MFMA16(ah0, kfh[t][0], sacc[t]);
            sacc[t] = MFMA16(ah0, kfl[t][0], sacc[t]);
            sacc[t] = MFMA16(al0, kfh[t][0], sacc[t]);
        }
        #pragma unroll
        for (int t = 0; t < 4; ++t) {
            sacc[t] = MFMA16(ah1, kfh[t][1], sacc[t]);
            sacc[t] = MFMA16(ah1, kfl[t][1], sacc[t]);
            sacc[t] = MFMA16(al1, kfh[t][1], sacc[t]);
        }

        float tmax = -1e30f;
        #pragma unroll
        for (int t = 0; t < 4; ++t)
            #pragma unroll
            for (int r = 0; r < 4; ++r) tmax = fmaxf(tmax, sacc[t][r]);
        float nm = fmaxf(m_r, tmax);
        s_r *= __expf(m_r - nm);
        float tt = 0.f;
        #pragma unroll
        for (int t = 0; t < 4; ++t)
            #pragma unroll
            for (int r = 0; r < 4; ++r) tt += __expf(sacc[t][r] - nm);
        s_r += tt;
        m_r = nm;
    }

    red[tid] = m_r;
    red[256 + tid] = s_r;
    __syncthreads();
    for (int off = 128; off > 0; off >>= 1) {
        if (tid < off) {
            float m2 = red[tid + off], s2 = red[256 + tid + off];
            float M = fmaxf(red[tid], m2);
            red[256 + tid] = red[256 + tid] * __expf(red[tid] - M) + s2 * __expf(m2 - M);
            red[tid] = M;
        }
        __syncthreads();
    }
    if (tid == 0) {
        pstats[((b << 7) + (hd << 4) + mt) * 2 + 0] = red[0];
        pstats[((b << 7) + (hd << 4) + mt) * 2 + 1] = red[256];
    }
}

__global__ __launch_bounds__(128)
void combine_kernel(const float* __restrict__ pstats, float* __restrict__ gstats)
{
    const int b = blockIdx.x, tid = threadIdx.x;
    __shared__ float rm[128], rs[128];
    rm[tid] = pstats[((b << 7) + tid) * 2 + 0];
    rs[tid] = pstats[((b << 7) + tid) * 2 + 1];
    __syncthreads();
    for (int off = 64; off > 0; off >>= 1) {
        if (tid < off) {
            float m2 = rm[tid + off], s2 = rs[tid + off];
            float M = fmaxf(rm[tid], m2);
            rs[tid] = rs[tid] * __expf(rm[tid] - M) + s2 * __expf(m2 - M);
            rm[tid] = M;
        }
        __syncthreads();
    }
    if (tid == 0) { gstats[b * 2] = rm[0]; gstats[b * 2 + 1] = rs[0]; }
}

// ---------------- pv: in-register softmax -> K=16 PV ----------------
__global__ __launch_bounds__(256, 2)
void pv_kernel(const unsigned short* __restrict__ Qh, const unsigned short* __restrict__ Ql,
               const unsigned short* __restrict__ Kh, const unsigned short* __restrict__ Kl,
               const unsigned short* __restrict__ Vh, const unsigned short* __restrict__ Vl,
               const float* __restrict__ gstats, float* __restrict__ out)
{
    const int tid = threadIdx.x;
    const int mt = blockIdx.x, hd = blockIdx.y, b = blockIdx.z;
    const int bh = b * HEAD + hd;
    const int lane = tid & 63, w = tid >> 6;
    const int r0 = lane & 15, c0 = (lane >> 4) << 3;

    // LDS: V tiles (16 KB) in main loop; 2 fp32 F regions (32.5 KB) in epilogue
    __shared__ __align__(16) unsigned char smraw[2 * 64 * 65 * 4];
    unsigned short* Vsh = (unsigned short*)smraw;
    unsigned short* Vsl = Vsh + 4096;
    float* F0 = (float*)smraw;
    float* F1 = F0 + 64 * 65;

    // K fragments: global -> reg, once (identical mapping to stats)
    const unsigned short* kh = Kh + (((size_t)bh * NN + (mt << 6)) << 6);
    const unsigned short* kl = Kl + (((size_t)bh * NN + (mt << 6)) << 6);
    bf16x8 kfh[4][2], kfl[4][2];
    #pragma unroll
    for (int t = 0; t < 4; ++t)
        #pragma unroll
        for (int s = 0; s < 2; ++s) {
            int off = (((t << 4) + r0) << 6) + (s << 5) + c0;
            kfh[t][s] = *(const bf16x8*)&kh[off];
            kfl[t][s] = *(const bf16x8*)&kl[off];
        }

    const unsigned short* qh = Qh + (((size_t)bh * NN) << 6);
    const unsigned short* ql = Ql + (((size_t)bh * NN) << 6);
    const unsigned short* vh = Vh + (((size_t)bh << 6) * NN);
    const unsigned short* vl = Vl + (((size_t)bh << 6) * NN);

    const float gmax = gstats[b * 2];
    const float ginv = 1.f / gstats[b * 2 + 1];

    f32x4 facc[4][4];   // [d-tile u][m-tile t], F^T partial over this wave's n
    #pragma unroll
    for (int u = 0; u < 4; ++u)
        #pragma unroll
        for (int t = 0; t < 4; ++t) facc[u][t] = (f32x4){0.f, 0.f, 0.f, 0.f};

    for (int nt = 0; nt < 16; ++nt) {
        const int nB = nt << 6;
        // stage V tile [64 d][64 n] hi/lo (swizzled)
        #pragma unroll
        for (int p = 0; p < 2; ++p) {
            int idx = (p << 8) + tid;
            int row = idx >> 3, c8 = (idx & 7) << 3;
            *(float4*)&Vsh[SW(row, c8)] = *(const float4*)&vh[(size_t)row * NN + nB + c8];
            *(float4*)&Vsl[SW(row, c8)] = *(const float4*)&vl[(size_t)row * NN + nB + c8];
        }
        // Q fragments for this wave's 16 n-rows: global -> reg
        const int qrow = nB + (w << 4) + r0;
        const size_t qb = ((size_t)qrow << 6) + c0;
        bf16x8 ah0 = *(const bf16x8*)&qh[qb];
        bf16x8 ah1 = *(const bf16x8*)&qh[qb + 32];
        bf16x8 al0 = *(const bf16x8*)&ql[qb];
        bf16x8 al1 = *(const bf16x8*)&ql[qb + 32];
        __syncthreads();   // V staged

        // logits: identical MFMA order to stats_kernel
        f32x4 sacc[4];
        #pragma unroll
        for (int t = 0; t < 4; ++t) sacc[t] = (f32x4){0.f, 0.f, 0.f, 0.f};
        #pragma unroll
        for (int t = 0; t < 4; ++t) {
            sacc[t] = MFMA16(ah0, kfh[t][0], sacc[t]);
            sacc[t] = MFMA16(ah0, kfl[t][0], sacc[t]);
            sacc[t] = MFMA16(al0, kfh[t][0], sacc[t]);
        }
        #pragma unroll
        for (int t = 0; t < 4; ++t) {
            sacc[t] = MFMA16(ah1, kfh[t][1], sacc[t]);
            sacc[t] = MFMA16(ah1, kfl[t][1], sacc[t]);
            sacc[t] = MFMA16(al1, kfh[t][1], sacc[t]);
        }

        // softmax in-register; C-layout == B-operand layout for K=16 MFMA
        short4v pah[4], pal[4];
        #pragma unroll
        for (int t = 0; t < 4; ++t) {
            union { unsigned short u[4]; short4v v; } Ph, Pl;
            #pragma unroll
            for (int r = 0; r < 4; ++r) {
                float a = __expf(sacc[t][r] - gmax) * ginv;
                unsigned short hh = bfh(a);
                Ph.u[r] = hh;
                Pl.u[r] = bfh(a - bf2f(hh));
            }
            pah[t] = Ph.v;
            pal[t] = Pl.v;
        }

        // PV: F^T[d][m] partial over this wave's 16 n (K=16 MFMA)
        const int vcol = (w << 4) + ((lane >> 4) << 2);
        #pragma unroll
        for (int u = 0; u < 4; ++u) {
            int vrow = (u << 4) + r0;
            short4v vah = *(const short4v*)&Vsh[SW(vrow, vcol)];
            short4v vbl = *(const short4v*)&Vsl[SW(vrow, vcol)];
            #pragma unroll
            for (int t = 0; t < 4; ++t) {
                facc[u][t] = mfma_pv(vah, pah[t], facc[u][t]);
                facc[u][t] = mfma_pv(vbl, pah[t], facc[u][t]);
                facc[u][t] = mfma_pv(vah, pal[t], facc[u][t]);
            }
        }
        __syncthreads();   // PV reads done before next stage / epilogue reuse
    }

    // ---- cross-wave reduction of partial F^T, then 2x2 avg-pool ----
    const int fr = (lane >> 4) << 2;
    if (w < 2) {
        float* Fw = (w == 0) ? F0 : F1;
        #pragma unroll
        for (int u = 0; u < 4; ++u)
            #pragma unroll
            for (int t = 0; t < 4; ++t)
                #pragma unroll
                for (int r = 0; r < 4; ++r)
                    Fw[((u << 4) + fr + r) * 65 + (t << 4) + r0] = facc[u][t][r];
    }
    __syncthreads();
    if (w >= 2) {
        float* Fw = (w == 2) ? F0 : F1;
        #pragma unroll
        for (int u = 0; u < 4; ++u)
            #pragma unroll
            for (int t = 0; t < 4; ++t)
                #pragma unroll
                for (int r = 0; r < 4; ++r)
                    Fw[((u << 4) + fr + r) * 65 + (t << 4) + r0] += facc[u][t][r];
    }
    __syncthreads();
    #pragma unroll
    for (int q = 0; q < 4; ++q) {
        int idx = (tid << 2) + q;
        int d = idx >> 4, wo = idx & 15;
        int m0 = wo << 1;
        float v = 0.25f * ((F0[d * 65 + m0]      + F1[d * 65 + m0]) +
                           (F0[d * 65 + m0 + 1]  + F1[d * 65 + m0 + 1]) +
                           (F0[d * 65 + 32 + m0] + F1[d * 65 + 32 + m0]) +
                           (F0[d * 65 + 33 + m0] + F1[d * 65 + 33 + m0]));
        out[(((size_t)(b * DIMC + (hd << 6) + d) << 4) + mt) * 16 + wo] = v;
    }
}

extern "C" void kernel_launch(void* const* d_in, const int* in_sizes, int n_in,
                              void* d_out, int out_size, void* d_ws, size_t ws_size,
                              hipStream_t stream)
{
    const float* x    = (const float*)d_in[0];
    const float* wq_w = (const float*)d_in[1];
    const float* wq_b = (const float*)d_in[2];
    const float* wk_w = (const float*)d_in[3];
    const float* wk_b = (const float*)d_in[4];
    const float* wv_w = (const float*)d_in[5];
    const float* wv_b = (const float*)d_in[6];
    const float* r_h  = (const float*)d_in[7];
    const float* r_w  = (const float*)d_in[8];
    float* out = (float*)d_out;

    const size_t PRN = (size_t)BB * HEAD * NN * DH;
    const size_t WSZ = (size_t)3 * DIMC * DIMC;
    unsigned short* Qh  = (unsigned short*)d_ws;
    unsigned short* Ql  = Qh + PRN;
    unsigned short* Kh  = Ql + PRN;
    unsigned short* Kl  = Kh + PRN;
    unsigned short* Vh  = Kl + PRN;
    unsigned short* Vl  = Vh + PRN;
    unsigned short* XTh = Vl + PRN;
    unsigned short* XTl = XTh + PRN;
    unsigned short* Wh  = XTl + PRN;
    unsigned short* Wl  = Wh + WSZ;
    float* pstats = (float*)(Wl + WSZ);
    float* gstats = pstats + BB * 128 * 2;

    prep_x<<<dim3(16, 8, 8), 256, 0, stream>>>(x, XTh, XTl);
    prep_w<<<dim3(64, 3), 256, 0, stream>>>(wq_w, wk_w, wv_w, Wh, Wl);
    qkv_gemm<<<dim3(64, 8, 3), 256, 0, stream>>>(XTh, XTl, Wh, Wl,
                                                 wq_b, wk_b, wv_b, r_h, r_w,
                                                 Qh, Ql, Kh, Kl, Vh, Vl);
    stats_kernel<<<dim3(16, 8, 8), 256, 0, stream>>>(Qh, Ql, Kh, Kl, pstats);
    combine_kernel<<<dim3(8), 128, 0, stream>>>(pstats, gstats);
    pv_kernel<<<dim3(16, 8, 8), 256, 0, stream>>>(Qh, Ql, Kh, Kl, Vh, Vl, gstats, out);
}

// Round 7
// 250.314 us; speedup vs baseline: 2.5762x; 1.0265x over previous
//
#include <hip/hip_runtime.h>
#include <hip/hip_bf16.h>
#include <math.h>

// MHSA: B=8, DIM=512, H=W=32, HEAD=8, DH=64, N=1024
// Round 7: flash-style single-pass attention (stats_kernel DELETED).
//  flash_pv: per (mt,hd,b) block, online-softmax QK^T -> in-register P ->
//            K=16 PV, per-wave (m,s) partials combined to block (m_B,s_B);
//            writes UNNORMALIZED pooled tile + pstats.
//  combine : per-batch logsumexp of 128 block partials -> gstats (unchanged).
//  finalize: out = pooled * exp(m_B - gmax_b) / gsum_b  (tiny, HBM-bound).
#define BB   8
#define DIMC 512
#define HEAD 8
#define DH   64
#define NN   1024
#define HW   32

typedef __attribute__((ext_vector_type(8))) __bf16 bf16x8;
typedef __attribute__((ext_vector_type(4))) float  f32x4;
typedef __attribute__((ext_vector_type(4))) short  short4v;

#define MFMA16(a, b, c) __builtin_amdgcn_mfma_f32_16x16x32_bf16((a), (b), (c), 0, 0, 0)

__device__ __forceinline__ f32x4 mfma_pv(short4v a, short4v b, f32x4 c) {
#if __has_builtin(__builtin_amdgcn_mfma_f32_16x16x16bf16_1k)
    return __builtin_amdgcn_mfma_f32_16x16x16bf16_1k(a, b, c, 0, 0, 0);
#else
    asm volatile("v_mfma_f32_16x16x16_bf16 %0, %1, %2, %0"
                 : "+v"(c) : "v"(a), "v"(b));
    return c;
#endif
}

// swizzled element offset in a [rows][64 bf16] LDS tile (rows = 128 B).
__device__ __forceinline__ int SW(int row, int col) {
    return (row << 6) + (col ^ ((row & 7) << 3));
}

__device__ __forceinline__ unsigned short bfh(float v) {   // fp32 -> bf16 (RNE)
    unsigned int u = __float_as_uint(v);
    return (unsigned short)((u + 0x7fffu + ((u >> 16) & 1u)) >> 16);
}
__device__ __forceinline__ float bf2f(unsigned short h) {
    return __uint_as_float(((unsigned int)h) << 16);
}

// ---------------- prep: x transpose + split ----------------
__global__ __launch_bounds__(256)
void prep_x(const float* __restrict__ x,
            unsigned short* __restrict__ XTh, unsigned short* __restrict__ XTl)
{
    const int tid = threadIdx.x;
    const int nt = blockIdx.x;     // 16
    const int ct = blockIdx.y;     // 8
    const int b  = blockIdx.z;     // 8
    const int c0 = ct << 6, n0 = nt << 6;

    __shared__ float XsT[64][68];  // [n][c]

    #pragma unroll
    for (int p = 0; p < 4; ++p) {
        int idx = tid + (p << 8);
        int cr = idx >> 4;
        int nc4 = (idx & 15) << 2;
        float4 v = *(const float4*)&x[((size_t)b * DIMC + c0 + cr) * NN + n0 + nc4];
        XsT[nc4 + 0][cr] = v.x;
        XsT[nc4 + 1][cr] = v.y;
        XsT[nc4 + 2][cr] = v.z;
        XsT[nc4 + 3][cr] = v.w;
    }
    __syncthreads();
    #pragma unroll
    for (int p = 0; p < 4; ++p) {
        int idx = tid + (p << 8);
        int n = idx >> 4;
        int c4 = (idx & 15) << 2;
        float4 v = *(const float4*)&XsT[n][c4];
        float vv[4] = {v.x, v.y, v.z, v.w};
        union { unsigned short u[4]; uint2 w; } ph, pl;
        #pragma unroll
        for (int j = 0; j < 4; ++j) {
            unsigned short hh = bfh(vv[j]);
            ph.u[j] = hh;
            pl.u[j] = bfh(vv[j] - bf2f(hh));
        }
        size_t off = ((size_t)(b * NN + n0 + n)) * DIMC + c0 + c4;
        *(uint2*)&XTh[off] = ph.w;
        *(uint2*)&XTl[off] = pl.w;
    }
}

// ---------------- prep: weight split ----------------
__global__ __launch_bounds__(256)
void prep_w(const float* __restrict__ wq, const float* __restrict__ wk,
            const float* __restrict__ wv,
            unsigned short* __restrict__ Wh, unsigned short* __restrict__ Wl)
{
    const int z = blockIdx.y;
    const float* src = (z == 0) ? wq : (z == 1) ? wk : wv;
    const size_t zb = (size_t)z * DIMC * DIMC;
    #pragma unroll
    for (int p = 0; p < 4; ++p) {
        size_t i = (size_t)blockIdx.x * 4096 + (p << 10) + (threadIdx.x << 2);
        float4 v = *(const float4*)&src[i];
        float vv[4] = {v.x, v.y, v.z, v.w};
        union { unsigned short u[4]; uint2 w; } ph, pl;
        #pragma unroll
        for (int j = 0; j < 4; ++j) {
            unsigned short hh = bfh(vv[j]);
            ph.u[j] = hh;
            pl.u[j] = bfh(vv[j] - bf2f(hh));
        }
        *(uint2*)&Wh[zb + i] = ph.w;
        *(uint2*)&Wl[zb + i] = pl.w;
    }
}

// ---------------- qkv GEMM (MFMA) ----------------
__global__ __launch_bounds__(256)
void qkv_gemm(const unsigned short* __restrict__ XTh, const unsigned short* __restrict__ XTl,
              const unsigned short* __restrict__ Wh, const unsigned short* __restrict__ Wl,
              const float* __restrict__ wq_b, const float* __restrict__ wk_b,
              const float* __restrict__ wv_b,
              const float* __restrict__ r_h, const float* __restrict__ r_w,
              unsigned short* __restrict__ Qh, unsigned short* __restrict__ Ql,
              unsigned short* __restrict__ Kh, unsigned short* __restrict__ Kl,
              unsigned short* __restrict__ Vh, unsigned short* __restrict__ Vl)
{
    const int tid = threadIdx.x;
    const int z = blockIdx.z, hd = blockIdx.y;
    const int gn = blockIdx.x << 7;
    const int b = gn >> 10, posb = gn & 1023;
    const int oB = hd << 6;
    const int lane = tid & 63, w = tid >> 6;

    __shared__ __align__(16) unsigned short sm[24576];  // 48 KB
    unsigned short* Ah = sm;
    unsigned short* Al = sm + 4096;
    unsigned short* Bh = sm + 8192;
    unsigned short* Bl = sm + 16384;

    const float* bias = (z == 0) ? wq_b : (z == 1) ? wk_b : wv_b;
    const unsigned short* wsh = Wh + (size_t)z * DIMC * DIMC + (size_t)oB * DIMC;
    const unsigned short* wsl = Wl + (size_t)z * DIMC * DIMC + (size_t)oB * DIMC;
    const unsigned short* xth = XTh + ((size_t)(b * NN + posb)) * DIMC;
    const unsigned short* xtl = XTl + ((size_t)(b * NN + posb)) * DIMC;

    f32x4 acc[8];
    #pragma unroll
    for (int t = 0; t < 8; ++t) acc[t] = (f32x4){0.f, 0.f, 0.f, 0.f};

    for (int ks = 0; ks < 8; ++ks) {
        const int c0 = ks << 6;
        #pragma unroll
        for (int p = 0; p < 2; ++p) {
            int idx = (p << 8) + tid;
            int row = idx >> 3, col8 = (idx & 7) << 3;
            size_t g = (size_t)row * DIMC + c0 + col8;
            *(float4*)&Ah[SW(row, col8)] = *(const float4*)&wsh[g];
            *(float4*)&Al[SW(row, col8)] = *(const float4*)&wsl[g];
        }
        #pragma unroll
        for (int p = 0; p < 4; ++p) {
            int idx = (p << 8) + tid;
            int row = idx >> 3, col8 = (idx & 7) << 3;
            size_t g = (size_t)row * DIMC + c0 + col8;
            *(float4*)&Bh[SW(row, col8)] = *(const float4*)&xth[g];
            *(float4*)&Bl[SW(row, col8)] = *(const float4*)&xtl[g];
        }
        __syncthreads();

        const int ar = (w << 4) + (lane & 15);
        const int kc = (lane >> 4) << 3;
        bf16x8 ah[2], al[2];
        ah[0] = *(const bf16x8*)&Ah[SW(ar, kc)];
        ah[1] = *(const bf16x8*)&Ah[SW(ar, 32 + kc)];
        al[0] = *(const bf16x8*)&Al[SW(ar, kc)];
        al[1] = *(const bf16x8*)&Al[SW(ar, 32 + kc)];
        #pragma unroll
        for (int t = 0; t < 8; ++t) {
            int br = (t << 4) + (lane & 15);
            #pragma unroll
            for (int s = 0; s < 2; ++s) {
                bf16x8 xh = *(const bf16x8*)&Bh[SW(br, s * 32 + kc)];
                bf16x8 xl = *(const bf16x8*)&Bl[SW(br, s * 32 + kc)];
                acc[t] = MFMA16(ah[s], xh, acc[t]);
                acc[t] = MFMA16(ah[s], xl, acc[t]);
                acc[t] = MFMA16(al[s], xh, acc[t]);
            }
        }
        __syncthreads();
    }

    float* F = (float*)sm;    // [64][132]
    #pragma unroll
    for (int t = 0; t < 8; ++t) {
        int n = (t << 4) + (lane & 15);
        #pragma unroll
        for (int r = 0; r < 4; ++r) {
            int o = (w << 4) + ((lane >> 4) << 2) + r;
            F[o * 132 + n] = acc[t][r];
        }
    }
    __syncthreads();

    const size_t bh = (size_t)(b * HEAD + hd);
    if (z != 2) {
        unsigned short* Dh = (z == 0) ? Qh : Kh;
        unsigned short* Dl = (z == 0) ? Ql : Kl;
        #pragma unroll
        for (int p = 0; p < 8; ++p) {
            int idx = (p << 8) + tid;
            int n = idx >> 4, d0 = (idx & 15) << 2;
            union { unsigned short u[4]; uint2 v; } ph, pl;
            #pragma unroll
            for (int i = 0; i < 4; ++i) {
                int d = d0 + i;
                float val = F[d * 132 + n] + bias[oB + d];
                if (z == 1) {
                    int m = posb + n;
                    val += r_h[(size_t)(oB + d) * HW + (m & 31)]
                         + r_w[(size_t)(oB + d) * HW + (m >> 5)];
                }
                unsigned short hh = bfh(val);
                ph.u[i] = hh;
                pl.u[i] = bfh(val - bf2f(hh));
            }
            size_t off = (((size_t)bh * NN + posb + n) << 6) + d0;
            *(uint2*)&Dh[off] = ph.v;
            *(uint2*)&Dl[off] = pl.v;
        }
    } else {
        #pragma unroll
        for (int p = 0; p < 8; ++p) {
            int idx = (p << 8) + tid;
            int d = idx >> 5, n0 = (idx & 31) << 2;
            float4 v = *(const float4*)&F[d * 132 + n0];
            float vv[4] = {v.x, v.y, v.z, v.w};
            float bia = bias[oB + d];
            union { unsigned short u[4]; uint2 w2; } ph, pl;
            #pragma unroll
            for (int j = 0; j < 4; ++j) {
                float val = vv[j] + bia;
                unsigned short hh = bfh(val);
                ph.u[j] = hh;
                pl.u[j] = bfh(val - bf2f(hh));
            }
            size_t off = (((size_t)bh << 6) + d) * NN + posb + n0;
            *(uint2*)&Vh[off] = ph.w2;
            *(uint2*)&Vl[off] = pl.w2;
        }
    }
}

// ---------------- flash_pv: single-pass online-softmax attention ----------------
__global__ __launch_bounds__(256, 2)
void flash_pv(const unsigned short* __restrict__ Qh, const unsigned short* __restrict__ Ql,
              const unsigned short* __restrict__ Kh, const unsigned short* __restrict__ Kl,
              const unsigned short* __restrict__ Vh, const unsigned short* __restrict__ Vl,
              float* __restrict__ pooled, float* __restrict__ pstats)
{
    const int tid = threadIdx.x;
    const int mt = blockIdx.x, hd = blockIdx.y, b = blockIdx.z;
    const int bh = b * HEAD + hd;
    const int lane = tid & 63, w = tid >> 6;
    const int r0 = lane & 15, c0 = (lane >> 4) << 3;

    // LDS: V tiles (16 KB) in main loop; 2 fp32 F regions (32.5 KB) in epilogue
    __shared__ __align__(16) unsigned char smraw[2 * 64 * 65 * 4];
    unsigned short* Vsh = (unsigned short*)smraw;
    unsigned short* Vsl = Vsh + 4096;
    float* F0 = (float*)smraw;
    float* F1 = F0 + 64 * 65;
    __shared__ float bm[4], bs[4];

    // K fragments: global -> reg, once
    const unsigned short* kh = Kh + (((size_t)bh * NN + (mt << 6)) << 6);
    const unsigned short* kl = Kl + (((size_t)bh * NN + (mt << 6)) << 6);
    bf16x8 kfh[4][2], kfl[4][2];
    #pragma unroll
    for (int t = 0; t < 4; ++t)
        #pragma unroll
        for (int s = 0; s < 2; ++s) {
            int off = (((t << 4) + r0) << 6) + (s << 5) + c0;
            kfh[t][s] = *(const bf16x8*)&kh[off];
            kfl[t][s] = *(const bf16x8*)&kl[off];
        }

    const unsigned short* qh = Qh + (((size_t)bh * NN) << 6);
    const unsigned short* ql = Ql + (((size_t)bh * NN) << 6);
    const unsigned short* vh = Vh + (((size_t)bh << 6) * NN);
    const unsigned short* vl = Vl + (((size_t)bh << 6) * NN);

    float m_w = -1e30f;   // wave-uniform running max (this wave's n-slice, all 64 m)
    float s_r = 0.f;      // per-lane partial sumexp (consistent normalizer m_w)

    f32x4 facc[4][4];     // [d-tile u][m-tile t], unnormalized F^T partial
    #pragma unroll
    for (int u = 0; u < 4; ++u)
        #pragma unroll
        for (int t = 0; t < 4; ++t) facc[u][t] = (f32x4){0.f, 0.f, 0.f, 0.f};

    for (int nt = 0; nt < 16; ++nt) {
        const int nB = nt << 6;
        // stage V tile [64 d][64 n] hi/lo (swizzled)
        #pragma unroll
        for (int p = 0; p < 2; ++p) {
            int idx = (p << 8) + tid;
            int row = idx >> 3, c8 = (idx & 7) << 3;
            *(float4*)&Vsh[SW(row, c8)] = *(const float4*)&vh[(size_t)row * NN + nB + c8];
            *(float4*)&Vsl[SW(row, c8)] = *(const float4*)&vl[(size_t)row * NN + nB + c8];
        }
        // Q fragments for this wave's 16 n-rows: global -> reg
        const int qrow = nB + (w << 4) + r0;
        const size_t qb = ((size_t)qrow << 6) + c0;
        bf16x8 ah0 = *(const bf16x8*)&qh[qb];
        bf16x8 ah1 = *(const bf16x8*)&qh[qb + 32];
        bf16x8 al0 = *(const bf16x8*)&ql[qb];
        bf16x8 al1 = *(const bf16x8*)&ql[qb + 32];
        __syncthreads();   // V staged

        // logits S (3-term split)
        f32x4 sacc[4];
        #pragma unroll
        for (int t = 0; t < 4; ++t) sacc[t] = (f32x4){0.f, 0.f, 0.f, 0.f};
        #pragma unroll
        for (int t = 0; t < 4; ++t) {
            sacc[t] = MFMA16(ah0, kfh[t][0], sacc[t]);
            sacc[t] = MFMA16(ah0, kfl[t][0], sacc[t]);
            sacc[t] = MFMA16(al0, kfh[t][0], sacc[t]);
        }
        #pragma unroll
        for (int t = 0; t < 4; ++t) {
            sacc[t] = MFMA16(ah1, kfh[t][1], sacc[t]);
            sacc[t] = MFMA16(ah1, kfl[t][1], sacc[t]);
            sacc[t] = MFMA16(al1, kfh[t][1], sacc[t]);
        }

        // online max: lane max -> wave max (shfl butterfly), rescale on increase
        float tmax = -1e30f;
        #pragma unroll
        for (int t = 0; t < 4; ++t)
            #pragma unroll
            for (int r = 0; r < 4; ++r) tmax = fmaxf(tmax, sacc[t][r]);
        #pragma unroll
        for (int off = 1; off < 64; off <<= 1)
            tmax = fmaxf(tmax, __shfl_xor(tmax, off, 64));
        if (tmax > m_w) {                      // wave-uniform branch
            float sc = __expf(m_w - tmax);     // exp(-inf)=0 on first tile
            s_r *= sc;
            #pragma unroll
            for (int u = 0; u < 4; ++u)
                #pragma unroll
                for (int t = 0; t < 4; ++t) facc[u][t] *= sc;
            m_w = tmax;
        }

        // P = exp(S - m_w) in-register, split hi/lo; accumulate s
        short4v pah[4], pal[4];
        #pragma unroll
        for (int t = 0; t < 4; ++t) {
            union { unsigned short u[4]; short4v v; } Ph, Pl;
            #pragma unroll
            for (int r = 0; r < 4; ++r) {
                float a = __expf(sacc[t][r] - m_w);
                s_r += a;
                unsigned short hh = bfh(a);
                Ph.u[r] = hh;
                Pl.u[r] = bfh(a - bf2f(hh));
            }
            pah[t] = Ph.v;
            pal[t] = Pl.v;
        }

        // PV: F^T[d][m] partial over this wave's 16 n (K=16 MFMA)
        const int vcol = (w << 4) + ((lane >> 4) << 2);
        #pragma unroll
        for (int u = 0; u < 4; ++u) {
            int vrow = (u << 4) + r0;
            short4v vah = *(const short4v*)&Vsh[SW(vrow, vcol)];
            short4v vbl = *(const short4v*)&Vsl[SW(vrow, vcol)];
            #pragma unroll
            for (int t = 0; t < 4; ++t) {
                facc[u][t] = mfma_pv(vah, pah[t], facc[u][t]);
                facc[u][t] = mfma_pv(vbl, pah[t], facc[u][t]);
                facc[u][t] = mfma_pv(vah, pal[t], facc[u][t]);
            }
        }
        __syncthreads();   // PV reads done before next stage / epilogue reuse
    }

    // ---- per-wave s reduce, block (m_B, s_B) combine ----
    #pragma unroll
    for (int off = 1; off < 64; off <<= 1) s_r += __shfl_xor(s_r, off, 64);
    if (lane == 0) { bm[w] = m_w; bs[w] = s_r; }
    __syncthreads();
    const float m_B = fmaxf(fmaxf(bm[0], bm[1]), fmaxf(bm[2], bm[3]));
    const float s_B = bs[0] * __expf(bm[0] - m_B) + bs[1] * __expf(bm[1] - m_B)
                    + bs[2] * __expf(bm[2] - m_B) + bs[3] * __expf(bm[3] - m_B);
    const float fsc = __expf(m_w - m_B);
    #pragma unroll
    for (int u = 0; u < 4; ++u)
        #pragma unroll
        for (int t = 0; t < 4; ++t) facc[u][t] *= fsc;
    if (tid == 0) {
        pstats[((b << 7) + (hd << 4) + mt) * 2 + 0] = m_B;
        pstats[((b << 7) + (hd << 4) + mt) * 2 + 1] = s_B;
    }

    // ---- cross-wave reduction of partial F^T, then 2x2 avg-pool (unnormalized) ----
    const int fr = (lane >> 4) << 2;
    if (w < 2) {
        float* Fw = (w == 0) ? F0 : F1;
        #pragma unroll
        for (int u = 0; u < 4; ++u)
            #pragma unroll
            for (int t = 0; t < 4; ++t)
                #pragma unroll
                for (int r = 0; r < 4; ++r)
                    Fw[((u << 4) + fr + r) * 65 + (t << 4) + r0] = facc[u][t][r];
    }
    __syncthreads();
    if (w >= 2) {
        float* Fw = (w == 2) ? F0 : F1;
        #pragma unroll
        for (int u = 0; u < 4; ++u)
            #pragma unroll
            for (int t = 0; t < 4; ++t)
                #pragma unroll
                for (int r = 0; r < 4; ++r)
                    Fw[((u << 4) + fr + r) * 65 + (t << 4) + r0] += facc[u][t][r];
    }
    __syncthreads();
    #pragma unroll
    for (int q = 0; q < 4; ++q) {
        int idx = (tid << 2) + q;
        int d = idx >> 4, wo = idx & 15;
        int m0 = wo << 1;
        float v = 0.25f * ((F0[d * 65 + m0]      + F1[d * 65 + m0]) +
                           (F0[d * 65 + m0 + 1]  + F1[d * 65 + m0 + 1]) +
                           (F0[d * 65 + 32 + m0] + F1[d * 65 + 32 + m0]) +
                           (F0[d * 65 + 33 + m0] + F1[d * 65 + 33 + m0]));
        pooled[(((size_t)(b * DIMC + (hd << 6) + d) << 4) + mt) * 16 + wo] = v;
    }
}

__global__ __launch_bounds__(128)
void combine_kernel(const float* __restrict__ pstats, float* __restrict__ gstats)
{
    const int b = blockIdx.x, tid = threadIdx.x;
    __shared__ float rm[128], rs[128];
    rm[tid] = pstats[((b << 7) + tid) * 2 + 0];
    rs[tid] = pstats[((b << 7) + tid) * 2 + 1];
    __syncthreads();
    for (int off = 64; off > 0; off >>= 1) {
        if (tid < off) {
            float m2 = rm[tid + off], s2 = rs[tid + off];
            float M = fmaxf(rm[tid], m2);
            rs[tid] = rs[tid] * __expf(rm[tid] - M) + s2 * __expf(m2 - M);
            rm[tid] = M;
        }
        __syncthreads();
    }
    if (tid == 0) { gstats[b * 2] = rm[0]; gstats[b * 2 + 1] = rs[0]; }
}

// ---------------- finalize: scale pooled by exp(m_B-gmax)/gsum ----------------
__global__ __launch_bounds__(256)
void finalize(const float* __restrict__ pooled, const float* __restrict__ pstats,
              const float* __restrict__ gstats, float* __restrict__ out)
{
    const int j = blockIdx.x * 256 + threadIdx.x;   // float4 index, 262144 total
    const int e = j << 2;
    const int mt = (e >> 4) & 15;
    const int c  = e >> 8;
    const int b  = c >> 9;
    const int hd = (c >> 6) & 7;
    const int sidx = (b << 7) + (hd << 4) + mt;
    const float s = __expf(pstats[sidx * 2] - gstats[b * 2]) / gstats[b * 2 + 1];
    float4 v = *(const float4*)&pooled[e];
    v.x *= s; v.y *= s; v.z *= s; v.w *= s;
    *(float4*)&out[e] = v;
}

extern "C" void kernel_launch(void* const* d_in, const int* in_sizes, int n_in,
                              void* d_out, int out_size, void* d_ws, size_t ws_size,
                              hipStream_t stream)
{
    const float* x    = (const float*)d_in[0];
    const float* wq_w = (const float*)d_in[1];
    const float* wq_b = (const float*)d_in[2];
    const float* wk_w = (const float*)d_in[3];
    const float* wk_b = (const float*)d_in[4];
    const float* wv_w = (const float*)d_in[5];
    const float* wv_b = (const float*)d_in[6];
    const float* r_h  = (const float*)d_in[7];
    const float* r_w  = (const float*)d_in[8];
    float* out = (float*)d_out;

    const size_t PRN = (size_t)BB * HEAD * NN * DH;
    const size_t WSZ = (size_t)3 * DIMC * DIMC;
    unsigned short* Qh  = (unsigned short*)d_ws;
    unsigned short* Ql  = Qh + PRN;
    unsigned short* Kh  = Ql + PRN;
    unsigned short* Kl  = Kh + PRN;
    unsigned short* Vh  = Kl + PRN;
    unsigned short* Vl  = Vh + PRN;
    unsigned short* XTh = Vl + PRN;
    unsigned short* XTl = XTh + PRN;
    unsigned short* Wh  = XTl + PRN;
    unsigned short* Wl  = Wh + WSZ;
    float* pstats = (float*)(Wl + WSZ);
    float* gstats = pstats + BB * 128 * 2;
    // pooled (4 MB fp32) overlays XT region — XT is dead after qkv_gemm.
    float* pooled = (float*)XTh;

    prep_x<<<dim3(16, 8, 8), 256, 0, stream>>>(x, XTh, XTl);
    prep_w<<<dim3(64, 3), 256, 0, stream>>>(wq_w, wk_w, wv_w, Wh, Wl);
    qkv_gemm<<<dim3(64, 8, 3), 256, 0, stream>>>(XTh, XTl, Wh, Wl,
                                                 wq_b, wk_b, wv_b, r_h, r_w,
                                                 Qh, Ql, Kh, Kl, Vh, Vl);
    flash_pv<<<dim3(16, 8, 8), 256, 0, stream>>>(Qh, Ql, Kh, Kl, Vh, Vl,
                                                 pooled, pstats);
    combine_kernel<<<dim3(8), 128, 0, stream>>>(pstats, gstats);
    finalize<<<dim3(1024), 256, 0, stream>>>(pooled, pstats, gstats, out);
}